// Round 13
// baseline (315.347 us; speedup 1.0000x reference)
//
#include <hip/hip_runtime.h>
#include <hip/hip_bf16.h>
#include <math.h>

#define BB 16
#define NN 2048

typedef short bf16x8 __attribute__((ext_vector_type(8)));
typedef float f32x4 __attribute__((ext_vector_type(4)));
typedef unsigned long long u64;

#define MFMA(a, b, c) __builtin_amdgcn_mfma_f32_16x16x32_bf16(a, b, c, 0, 0, 0)

static __device__ __forceinline__ short f2bf(float f) {
  union { float f; unsigned u; } v; v.f = f;
  unsigned r = v.u + 0x7fffu + ((v.u >> 16) & 1u);
  return (short)(r >> 16);
}
static __device__ __forceinline__ short f2bf_hw(float f) {
  unsigned u;
  asm("v_cvt_pk_bf16_f32 %0, %1, %1" : "=v"(u) : "v"(f));
  return (short)u;
}
static __device__ __forceinline__ unsigned f2bf2(float lo, float hi) {
  unsigned u;
  asm("v_cvt_pk_bf16_f32 %0, %1, %2" : "=v"(u) : "v"(lo), "v"(hi));
  return u;
}

// ---------------- K0: fused weight-pack (blocks 0..743) + h/xx compute (744..1255) ----------
__global__ __launch_bounds__(64) void k_prep(
    const float* __restrict__ w1, const float* __restrict__ w3,
    const float* __restrict__ w2, const float* __restrict__ w4,
    const float* __restrict__ a1_att, const float* __restrict__ a2_att,
    const float* __restrict__ a1_w, const float* __restrict__ a2_w,
    const float* __restrict__ wf,
    short* __restrict__ w1f, short* __restrict__ w3f,
    short* __restrict__ w2f, short* __restrict__ w4f,
    short* __restrict__ wa1f, short* __restrict__ wa2f,
    short* __restrict__ wp1f, short* __restrict__ wp2f,
    short* __restrict__ wff,
    const float* __restrict__ x, const float* __restrict__ lw,
    const float* __restrict__ ls, const float* __restrict__ lb,
    float* __restrict__ h, float* __restrict__ xx) {
  int bb = blockIdx.x;
  if (bb >= 744) {
    // h = relu(bn(conv1d(x))); xx = ||h||^2 (same order as knn inner product)
    int p = (bb - 744) * 64 + threadIdx.x;
    int b = p >> 11;
    int n = p & (NN - 1);
    const float* xb = x + (size_t)b * 3 * NN + n;
    float x0 = xb[0], x1 = xb[NN], x2 = xb[2 * NN];
    float hv[8];
    float ss = 0.f;
#pragma unroll
    for (int o = 0; o < 8; ++o) {
      float v = x0 * lw[o * 3 + 0] + x1 * lw[o * 3 + 1] + x2 * lw[o * 3 + 2];
      v = fmaxf(v * ls[o] + lb[o], 0.f);
      hv[o] = v;
      ss += v * v;
    }
    float4* hp = (float4*)(h + (size_t)p * 8);
    hp[0] = make_float4(hv[0], hv[1], hv[2], hv[3]);
    hp[1] = make_float4(hv[4], hv[5], hv[6], hv[7]);
    xx[p] = ss;
    return;
  }
  const float* src;
  short* dst;
  int O, C, base;
  if (bb < 4)        { src = w1;     dst = w1f;  O = 64;  C = 16;  base = 0; }
  else if (bb < 8)   { src = w3;     dst = w3f;  O = 64;  C = 16;  base = 4; }
  else if (bb < 24)  { src = w2;     dst = w2f;  O = 128; C = 64;  base = 8; }
  else if (bb < 40)  { src = w4;     dst = w4f;  O = 128; C = 64;  base = 24; }
  else if (bb < 72)  { src = a1_att; dst = wa1f; O = 128; C = 128; base = 40; }
  else if (bb < 104) { src = a2_att; dst = wa2f; O = 128; C = 128; base = 72; }
  else if (bb < 168) { src = a1_w;   dst = wp1f; O = 256; C = 128; base = 104; }
  else if (bb < 232) { src = a2_w;   dst = wp2f; O = 256; C = 128; base = 168; }
  else               { src = wf;     dst = wff;  O = 512; C = 512; base = 232; }
  int blk = bb - base;
  int NCT = O >> 4;
  int ct = blk % NCT;
  int kt = blk / NCT;
  int l = threadIdx.x;
  int col = ct * 16 + (l & 15);
  bf16x8 v;
#pragma unroll
  for (int i = 0; i < 8; ++i) {
    int k = kt * 32 + ((l >> 4) << 3) + i;
    v[i] = (k < C) ? f2bf(src[(size_t)col * C + k]) : (short)0;
  }
  ((bf16x8*)dst)[(size_t)blk * 64 + l] = v;
}

// ---------------- K2: kNN top-16, TWO queries per lane ----------------
// 256 blocks x 256 thr (4 waves). Block = 128 queries; lane owns qbase+lane (A) and
// qbase+64+lane (B). Wave w scans slice [w*512,(w+1)*512): candidate read ONCE into regs,
// evaluated for both queries -> LDS reads per eval halved (the measured bottleneck).
// Shared per-query thresholds (atomicMax), exact keys/tie-order unchanged.
__global__ __launch_bounds__(256, 2) void k_knn(const float* __restrict__ h,
                                                const float* __restrict__ xx,
                                                int* __restrict__ knn_idx) {
  __shared__ __align__(16) unsigned char smem[52224];
  float4* sh4 = (float4*)smem;                 // [4][64][2] float4 = 8192
  float* sxx = (float*)(smem + 8192);          // [4][64] = 1024
  unsigned* thr = (unsigned*)(smem + 9216);    // [128] = 512
  u64* stkb = (u64*)(smem + 9728);             // [256][17] u64 = 34816 (end 44544)

  int tid = threadIdx.x;
  int lane = tid & 63;
  int w = tid >> 6;
  int blk = blockIdx.x;
  int b = blk >> 4;                 // 16 blocks per batch
  int qbase = (blk & 15) << 7;      // 128 queries per block
  int qA = qbase + lane;
  int qB = qbase + 64 + lane;
  const float* hb = h + ((size_t)b << 11) * 8;
  const float* xxb = xx + ((size_t)b << 11);

  float4 qa0 = *(const float4*)(hb + (size_t)qA * 8);
  float4 qa1 = *(const float4*)(hb + (size_t)qA * 8 + 4);
  float4 qb0 = *(const float4*)(hb + (size_t)qB * 8);
  float4 qb1 = *(const float4*)(hb + (size_t)qB * 8 + 4);
  float xqA = xxb[qA];
  float xqB = xxb[qB];

  if (tid < 128) thr[tid] = 0x007FFFFFu;  // key(-inf): prune nothing
  __syncthreads();

  u64* stkrow = stkb + tid * 17;   // A slots [0..7], B slots [8..15]
  u64 aA[16], aB[16];
#pragma unroll
  for (int i = 0; i < 16; ++i) { aA[i] = 0ULL; aB[i] = 0ULL; }
  int cA = 0, cB = 0;

  auto mkkey = [&](float d, int mg) -> u64 {
    unsigned uu = __float_as_uint(d);
    unsigned key = ((int)uu >= 0) ? (uu | 0x80000000u) : ~uu;
    return ((u64)key << 32) | (unsigned)(NN - 1 - mg);
  };
  auto decode = [&](unsigned t32) -> float {
    unsigned tu = (t32 & 0x80000000u) ? (t32 & 0x7fffffffu) : ~t32;
    return __uint_as_float(tu);
  };

  auto sort16 = [&](u64 (&c)[16]) {
#pragma unroll
    for (int k = 2; k <= 16; k <<= 1)
#pragma unroll
      for (int j = k >> 1; j > 0; j >>= 1)
#pragma unroll
        for (int i = 0; i < 16; ++i) {
          int l = i ^ j;
          if (l > i) {
            bool up = ((i & k) == 0);
            u64 xi = c[i], xl = c[l];
            bool sw = up ? (xi > xl) : (xi < xl);
            if (sw) { c[i] = xl; c[l] = xi; }
          }
        }
  };

  auto flush8 = [&](int sbase_, u64 (&a)[16], int& cnt) {
    u64 c[8];
#pragma unroll
    for (int j = 0; j < 8; ++j) {
      u64 v = stkrow[sbase_ + j];
      c[j] = (j < cnt) ? v : 0ULL;
    }
    cnt = 0;
#pragma unroll
    for (int k = 2; k <= 8; k <<= 1)
#pragma unroll
      for (int j = k >> 1; j > 0; j >>= 1)
#pragma unroll
        for (int i = 0; i < 8; ++i) {
          int l = i ^ j;
          if (l > i) {
            bool up = ((i & k) == 0);
            u64 xi = c[i], xl = c[l];
            bool sw = up ? (xi > xl) : (xi < xl);
            if (sw) { c[i] = xl; c[l] = xi; }
          }
        }
    u64 m[16];
#pragma unroll
    for (int i = 0; i < 16; ++i) {
      u64 bi = (i < 8) ? c[7 - i] : 0ULL;
      m[i] = (a[i] > bi) ? a[i] : bi;
    }
#pragma unroll
    for (int j = 8; j > 0; j >>= 1)
#pragma unroll
      for (int i = 0; i < 16; ++i) {
        int l = i ^ j;
        if (l > i && m[i] > m[l]) { u64 t = m[i]; m[i] = m[l]; m[l] = t; }
      }
#pragma unroll
    for (int i = 0; i < 16; ++i) a[i] = m[i];
  };

  int sbase = w * 512;
  float4 r0, r1;
  float rx;
  {
    const float* cp = hb + (size_t)(sbase + lane) * 8;
    r0 = *(const float4*)cp;
    r1 = *(const float4*)(cp + 4);
    rx = xxb[sbase + lane];
  }
  for (int c2 = 0; c2 < 8; ++c2) {
    sh4[(w * 64 + lane) * 2 + 0] = r0;
    sh4[(w * 64 + lane) * 2 + 1] = r1;
    sxx[w * 64 + lane] = rx;
    if (c2 < 7) {
      const float* cp = hb + (size_t)(sbase + (c2 + 1) * 64 + lane) * 8;
      r0 = *(const float4*)cp;
      r1 = *(const float4*)(cp + 4);
      rx = xxb[sbase + (c2 + 1) * 64 + lane];
    }
    int mg0 = sbase + c2 * 64;
    int sstart = 0;
    if (c2 == 0) {
      // warm start both queries on the first 16 candidates (exact sort)
#pragma unroll
      for (int j = 0; j < 16; ++j) {
        float4 a0 = sh4[(w * 64 + j) * 2 + 0];
        float4 a1 = sh4[(w * 64 + j) * 2 + 1];
        float xm = sxx[w * 64 + j];
        float iA = qa0.x * a0.x + qa0.y * a0.y + qa0.z * a0.z + qa0.w * a0.w +
                   qa1.x * a1.x + qa1.y * a1.y + qa1.z * a1.z + qa1.w * a1.w;
        float iB = qb0.x * a0.x + qb0.y * a0.y + qb0.z * a0.z + qb0.w * a0.w +
                   qb1.x * a1.x + qb1.y * a1.y + qb1.z * a1.z + qb1.w * a1.w;
        aA[j] = mkkey(2.f * iA - xqA - xm, mg0 + j);
        aB[j] = mkkey(2.f * iB - xqB - xm, mg0 + j);
      }
      sort16(aA);
      sort16(aB);
      atomicMax(&thr[lane], (unsigned)(aA[0] >> 32));
      atomicMax(&thr[64 + lane], (unsigned)(aB[0] >> 32));
      sstart = 16;
    }
    for (int s16 = sstart; s16 < 64; s16 += 16) {
      float thrFA = decode(thr[lane]);
      float thrFB = decode(thr[64 + lane]);
#pragma unroll 1
      for (int s4 = 0; s4 < 16; s4 += 4) {
        int s = s16 + s4;
        float4 xm4 = *(const float4*)&sxx[w * 64 + s];
#pragma unroll
        for (int u = 0; u < 4; ++u) {
          float4 a0 = sh4[(w * 64 + s + u) * 2 + 0];
          float4 a1 = sh4[(w * 64 + s + u) * 2 + 1];
          float xm = (u == 0) ? xm4.x : (u == 1) ? xm4.y : (u == 2) ? xm4.z : xm4.w;
          float iA = qa0.x * a0.x + qa0.y * a0.y + qa0.z * a0.z + qa0.w * a0.w +
                     qa1.x * a1.x + qa1.y * a1.y + qa1.z * a1.z + qa1.w * a1.w;
          float dA = 2.f * iA - xqA - xm;
          if (dA >= thrFA) { stkrow[cA] = mkkey(dA, mg0 + s + u); cA++; }
          float iB = qb0.x * a0.x + qb0.y * a0.y + qb0.z * a0.z + qb0.w * a0.w +
                     qb1.x * a1.x + qb1.y * a1.y + qb1.z * a1.z + qb1.w * a1.w;
          float dB = 2.f * iB - xqB - xm;
          if (dB >= thrFB) { stkrow[8 + cB] = mkkey(dB, mg0 + s + u); cB++; }
        }
        if (__any((cA >= 5) || (cB >= 5))) {
          flush8(0, aA, cA);
          flush8(8, aB, cB);
          atomicMax(&thr[lane], (unsigned)(aA[0] >> 32));
          atomicMax(&thr[64 + lane], (unsigned)(aB[0] >> 32));
          thrFA = decode(thr[lane]);
          thrFB = decode(thr[64 + lane]);
        }
      }
    }
  }
  if (__any((cA > 0) || (cB > 0))) {
    flush8(0, aA, cA);
    flush8(8, aB, cB);
  }

  // ---- merge tree: 4 wave-lists per query -> 1 (overlay dead scan LDS) ----
  u64* M1 = (u64*)smem;                 // [256][17]
  u64* M2 = (u64*)(smem + 34816);       // [128][17]

  auto mergeLds = [&](u64 (&a)[16], const u64* src) {
    u64 m[16];
#pragma unroll
    for (int i = 0; i < 16; ++i) {
      u64 bi = src[15 - i];
      m[i] = (a[i] > bi) ? a[i] : bi;
    }
#pragma unroll
    for (int j = 8; j > 0; j >>= 1)
#pragma unroll
      for (int i = 0; i < 16; ++i) {
        int l = i ^ j;
        if (l > i && m[i] > m[l]) { u64 t = m[i]; m[i] = m[l]; m[l] = t; }
      }
#pragma unroll
    for (int i = 0; i < 16; ++i) a[i] = m[i];
  };

  __syncthreads();
  if (w >= 2) {
    int base = (w - 2) * 128;
#pragma unroll
    for (int i = 0; i < 16; ++i) M1[(base + lane) * 17 + i] = aA[i];
#pragma unroll
    for (int i = 0; i < 16; ++i) M1[(base + 64 + lane) * 17 + i] = aB[i];
  }
  __syncthreads();
  if (w < 2) {
    int base = w * 128;
    mergeLds(aA, &M1[(base + lane) * 17]);
    mergeLds(aB, &M1[(base + 64 + lane) * 17]);
  }
  __syncthreads();
  if (w == 1) {
#pragma unroll
    for (int i = 0; i < 16; ++i) M2[lane * 17 + i] = aA[i];
#pragma unroll
    for (int i = 0; i < 16; ++i) M2[(64 + lane) * 17 + i] = aB[i];
  }
  __syncthreads();
  if (w == 0) {
    mergeLds(aA, &M2[lane * 17]);
    mergeLds(aB, &M2[(64 + lane) * 17]);
    int ids[16];
#pragma unroll
    for (int r = 0; r < 16; ++r)
      ids[r] = (NN - 1) - (int)(unsigned)(aA[15 - r] & 0xFFFFFFFFULL);
    int4* op = (int4*)(knn_idx + ((size_t)(b << 11) + qA) * 16);
    op[0] = make_int4(ids[0], ids[1], ids[2], ids[3]);
    op[1] = make_int4(ids[4], ids[5], ids[6], ids[7]);
    op[2] = make_int4(ids[8], ids[9], ids[10], ids[11]);
    op[3] = make_int4(ids[12], ids[13], ids[14], ids[15]);
#pragma unroll
    for (int r = 0; r < 16; ++r)
      ids[r] = (NN - 1) - (int)(unsigned)(aB[15 - r] & 0xFFFFFFFFULL);
    int4* op2 = (int4*)(knn_idx + ((size_t)(b << 11) + qB) * 16);
    op2[0] = make_int4(ids[0], ids[1], ids[2], ids[3]);
    op2[1] = make_int4(ids[4], ids[5], ids[6], ids[7]);
    op2[2] = make_int4(ids[8], ids[9], ids[10], ids[11]);
    op2[3] = make_int4(ids[12], ids[13], ids[14], ids[15]);
  }
}

// ---------------- K3: edge->conv1->conv2->att-score->pool (r11 body, swizzle reverted) ----
__global__ __launch_bounds__(512, 6) void k_branch_all(
    const float* __restrict__ h, const int* __restrict__ knn_idx,
    const short* __restrict__ w1f, const float* __restrict__ s1, const float* __restrict__ b1,
    const short* __restrict__ w2f, const float* __restrict__ s2, const float* __restrict__ b2,
    const short* __restrict__ wa1f,
    const short* __restrict__ w3f, const float* __restrict__ s3, const float* __restrict__ b3,
    const short* __restrict__ w4f, const float* __restrict__ s4, const float* __restrict__ b4,
    const short* __restrict__ wa2f,
    short* __restrict__ fout) {
  __shared__ __align__(16) unsigned char smem[53248];
  short (*e_s)[40]  = (short(*)[40])smem;              // [128][40], phases A-B only
  short (*g2_s)[136] = (short(*)[136])smem;            // [128][136], phases C-D (overlays e_s)
  short (*g1_s)[72] = (short(*)[72])(smem + 34816);    // [128][72]

  int br = blockIdx.y;
  const short* W1 = br ? w3f : w1f;
  const float* S1 = br ? s3 : s1;
  const float* B1 = br ? b3 : b1;
  const short* W2 = br ? w4f : w2f;
  const float* S2 = br ? s4 : s2;
  const float* B2 = br ? b4 : b2;
  const short* WA = br ? wa2f : wa1f;
  int KR = br ? 12 : 16;
  int FOFF = br ? 256 : 0;

  int tid = threadIdx.x;
  int lane = tid & 63;
  int w = tid >> 6;
  int lr = lane & 15;
  int lg = lane >> 4;
  int pbase = blockIdx.x * 8;
  const float* hb = h + ((size_t)(pbase & ~(NN - 1))) * 8;

  // Phase A: edge features
  if (tid < 128) {
    int t = tid >> 4, j = tid & 15;
    int p = pbase + t;
    const float* cp = h + (size_t)p * 8;
    bool real = (j < KR);
    unsigned d0 = 0, d1 = 0, d2 = 0, d3 = 0, c0 = 0, c1 = 0, c2 = 0, c3 = 0;
    if (real) {
      int id = knn_idx[(size_t)p * 16 + j];
      const float* np_ = hb + (size_t)id * 8;
      float cv0 = cp[0], cv1 = cp[1], cv2 = cp[2], cv3 = cp[3];
      float cv4 = cp[4], cv5 = cp[5], cv6 = cp[6], cv7 = cp[7];
      d0 = f2bf2(np_[0] - cv0, np_[1] - cv1);
      d1 = f2bf2(np_[2] - cv2, np_[3] - cv3);
      d2 = f2bf2(np_[4] - cv4, np_[5] - cv5);
      d3 = f2bf2(np_[6] - cv6, np_[7] - cv7);
      c0 = f2bf2(cv0, cv1); c1 = f2bf2(cv2, cv3);
      c2 = f2bf2(cv4, cv5); c3 = f2bf2(cv6, cv7);
    }
    *(uint4*)&e_s[tid][0] = make_uint4(d0, d1, d2, d3);
    *(uint4*)&e_s[tid][8] = make_uint4(c0, c1, c2, c3);
    *(uint4*)&e_s[tid][16] = make_uint4(0, 0, 0, 0);
    *(uint4*)&e_s[tid][24] = make_uint4(0, 0, 0, 0);
  }
  __syncthreads();

  // Phase B: conv1 16->64
  {
    int ct = w & 3;
    int rhalf = w >> 2;
    int o = ct * 16 + lr;
    bf16x8 bfrag = ((const bf16x8*)W1)[ct * 64 + lane];
    float scl = S1[o], bia = B1[o];
#pragma unroll
    for (int rt = 0; rt < 4; ++rt) {
      int rr = rhalf * 4 + rt;
      bf16x8 af = *(const bf16x8*)&e_s[rr * 16 + lr][lg * 8];
      f32x4 acc = {0.f, 0.f, 0.f, 0.f};
      acc = MFMA(af, bfrag, acc);
#pragma unroll
      for (int q = 0; q < 4; ++q) {
        g1_s[rr * 16 + lg * 4 + q][o] = f2bf_hw(fmaxf(acc[q] * scl + bia, 0.f));
      }
    }
  }
  __syncthreads();  // e_s dead; bytes become g2_s

  // Phase C: conv2 64->128
  float g2r[8][4];
  {
    int ct = w;
    int o = ct * 16 + lr;
    bf16x8 bf0 = ((const bf16x8*)W2)[(0 * 8 + ct) * 64 + lane];
    bf16x8 bf1 = ((const bf16x8*)W2)[(1 * 8 + ct) * 64 + lane];
    float scl = S2[o], bia = B2[o];
#pragma unroll
    for (int rt = 0; rt < 8; ++rt) {
      bf16x8 a0 = *(const bf16x8*)&g1_s[rt * 16 + lr][lg * 8];
      bf16x8 a1 = *(const bf16x8*)&g1_s[rt * 16 + lr][32 + lg * 8];
      f32x4 acc = {0.f, 0.f, 0.f, 0.f};
      acc = MFMA(a0, bf0, acc);
      acc = MFMA(a1, bf1, acc);
#pragma unroll
      for (int q = 0; q < 4; ++q) {
        float v = fmaxf(acc[q] * scl + bia, 0.f);
        g2r[rt][q] = v;
        g2_s[rt * 16 + lg * 4 + q][o] = f2bf_hw(v);
      }
    }
  }
  __syncthreads();

  // Phase D: att score (sigmoid)*g2, masked k-sum -> fbuf[p][FOFF..FOFF+128)
  {
    int ct = w;
    int o = ct * 16 + lr;
    bf16x8 bfr[4];
#pragma unroll
    for (int kt = 0; kt < 4; ++kt) bfr[kt] = ((const bf16x8*)WA)[(kt * 8 + ct) * 64 + lane];
#pragma unroll
    for (int rt = 0; rt < 8; ++rt) {
      f32x4 acc = {0.f, 0.f, 0.f, 0.f};
#pragma unroll
      for (int kt = 0; kt < 4; ++kt) {
        bf16x8 a = *(const bf16x8*)&g2_s[rt * 16 + lr][kt * 32 + lg * 8];
        acc = MFMA(a, bfr[kt], acc);
      }
      float v = 0.f;
#pragma unroll
      for (int q = 0; q < 4; ++q) {
        int jj = lg * 4 + q;
        float sg = __builtin_amdgcn_rcpf(1.f + __expf(-acc[q]));
        if (jj < KR) v += g2r[rt][q] * sg;
      }
      v += __shfl_xor(v, 16);
      v += __shfl_xor(v, 32);
      if (lane < 16)
        fout[(size_t)(pbase + rt) * 512 + FOFF + o] = f2bf_hw(v);
    }
  }
}

// ---------------- K3b: att conv 128->256 per branch, IN-PLACE on fbuf ----------------
__global__ __launch_bounds__(256, 4) void k_att(
    short* __restrict__ fb,
    const short* __restrict__ wp1f, const float* __restrict__ a1s, const float* __restrict__ a1b,
    const short* __restrict__ wp2f, const float* __restrict__ a2s, const float* __restrict__ a2b) {
  __shared__ short ptile[64][136];
  int br = blockIdx.y;
  const short* WP = br ? wp2f : wp1f;
  const float* SP = br ? a2s : a1s;
  const float* BP = br ? a2b : a1b;
  int FOFF = br ? 256 : 0;

  int tid = threadIdx.x;
  int lane = tid & 63;
  int w = tid >> 6;
  int lr = lane & 15;
  int lg = lane >> 4;
  int p0 = blockIdx.x * 64;

#pragma unroll
  for (int i = 0; i < 4; ++i) {
    int f = i * 256 + tid;
    int row = f >> 4, seg = f & 15;
    *(float4*)&ptile[row][seg * 8] =
        *(const float4*)(fb + (size_t)(p0 + row) * 512 + FOFF + seg * 8);
  }
  __syncthreads();

  bf16x8 af[4][4];
#pragma unroll
  for (int rt = 0; rt < 4; ++rt)
#pragma unroll
    for (int kt = 0; kt < 4; ++kt)
      af[rt][kt] = *(const bf16x8*)&ptile[rt * 16 + lr][kt * 32 + lg * 8];

#pragma unroll
  for (int cc = 0; cc < 4; ++cc) {
    int ct = w * 4 + cc;
    int o = ct * 16 + lr;
    bf16x8 bfr[4];
#pragma unroll
    for (int kt = 0; kt < 4; ++kt) bfr[kt] = ((const bf16x8*)WP)[(kt * 16 + ct) * 64 + lane];
    float scl = SP[o], bia = BP[o];
#pragma unroll
    for (int rt = 0; rt < 4; ++rt) {
      f32x4 acc = {0.f, 0.f, 0.f, 0.f};
#pragma unroll
      for (int kt = 0; kt < 4; ++kt) acc = MFMA(af[rt][kt], bfr[kt], acc);
#pragma unroll
      for (int q = 0; q < 4; ++q) {
        float v = fmaxf(acc[q] * scl + bia, 0.f);
        fb[(size_t)(p0 + rt * 16 + lg * 4 + q) * 512 + FOFF + o] = f2bf_hw(v);
      }
    }
  }
}

// ---------------- K4: out = relu(bn(f @ wf^T)) computed transposed ----------------
__global__ __launch_bounds__(256, 4) void k_final(
    const short* __restrict__ fbuf, const short* __restrict__ wff,
    const float* __restrict__ sf, const float* __restrict__ bfv,
    float* __restrict__ out) {
  __shared__ short b_s[256][72];
  int tid = threadIdx.x;
  int lane = tid & 63;
  int w = tid >> 6;
  int lr = lane & 15;
  int lg = lane >> 4;
  int ob = blockIdx.x;
  int p0 = blockIdx.y * 256;
  int rtg = ob * 4 + w;

  f32x4 acc[16];
#pragma unroll
  for (int ct = 0; ct < 16; ++ct) acc[ct] = (f32x4){0.f, 0.f, 0.f, 0.f};

  for (int kc = 0; kc < 512; kc += 64) {
    __syncthreads();
#pragma unroll
    for (int c = 0; c < 8; ++c) {
      int idx = c * 256 + tid;
      int row = idx >> 3, seg = idx & 7;
      *(float4*)&b_s[row][seg * 8] =
          *(const float4*)(fbuf + ((size_t)(p0 + row) * 512 + kc + seg * 8));
    }
    __syncthreads();
    int kt = kc >> 5;
    bf16x8 a0 = ((const bf16x8*)wff)[((size_t)(kt + 0) * 32 + rtg) * 64 + lane];
    bf16x8 a1 = ((const bf16x8*)wff)[((size_t)(kt + 1) * 32 + rtg) * 64 + lane];
#pragma unroll
    for (int ct = 0; ct < 16; ++ct) {
      bf16x8 bb0 = *(const bf16x8*)&b_s[ct * 16 + lr][lg * 8];
      bf16x8 bb1 = *(const bf16x8*)&b_s[ct * 16 + lr][32 + lg * 8];
      acc[ct] = MFMA(a0, bb0, acc[ct]);
      acc[ct] = MFMA(a1, bb1, acc[ct]);
    }
  }

  int b = p0 >> 11;
  int nb = p0 & (NN - 1);
#pragma unroll
  for (int q = 0; q < 4; ++q) {
    int o = rtg * 16 + lg * 4 + q;
    float scl = sf[o], bia = bfv[o];
#pragma unroll
    for (int ct = 0; ct < 16; ++ct) {
      int n = nb + ct * 16 + lr;
      float v = fmaxf(acc[ct][q] * scl + bia, 0.f);
      out[((size_t)b * 512 + o) * NN + n] = v;
    }
  }
}

extern "C" void kernel_launch(void* const* d_in, const int* in_sizes, int n_in,
                              void* d_out, int out_size, void* d_ws, size_t ws_size,
                              hipStream_t stream) {
  const float* x      = (const float*)d_in[0];
  const float* lw     = (const float*)d_in[1];
  const float* ls     = (const float*)d_in[2];
  const float* lb     = (const float*)d_in[3];
  const float* w1     = (const float*)d_in[4];
  const float* s1     = (const float*)d_in[5];
  const float* b1     = (const float*)d_in[6];
  const float* w2     = (const float*)d_in[7];
  const float* s2     = (const float*)d_in[8];
  const float* b2     = (const float*)d_in[9];
  const float* w3     = (const float*)d_in[10];
  const float* s3     = (const float*)d_in[11];
  const float* b3     = (const float*)d_in[12];
  const float* w4     = (const float*)d_in[13];
  const float* s4     = (const float*)d_in[14];
  const float* b4     = (const float*)d_in[15];
  const float* a1_att = (const float*)d_in[16];
  const float* a1_w   = (const float*)d_in[17];
  const float* a1_s   = (const float*)d_in[18];
  const float* a1_b   = (const float*)d_in[19];
  const float* a2_att = (const float*)d_in[20];
  const float* a2_w   = (const float*)d_in[21];
  const float* a2_s   = (const float*)d_in[22];
  const float* a2_b   = (const float*)d_in[23];
  const float* wf     = (const float*)d_in[24];
  const float* sf     = (const float*)d_in[25];
  const float* bf     = (const float*)d_in[26];
  float* out = (float*)d_out;

  char* ws = (char*)d_ws;
  float* h   = (float*)ws;                          ws += (size_t)BB * NN * 8 * 4;
  float* xx  = (float*)ws;                          ws += (size_t)BB * NN * 4;
  int* knn_idx = (int*)ws;                          ws += (size_t)BB * NN * 16 * 4;
  short* fbuf  = (short*)ws;                        ws += (size_t)BB * NN * 512 * 2;
  short* w1f   = (short*)ws;                        ws += 1 * 4 * 64 * 8 * 2;
  short* w3f   = (short*)ws;                        ws += 1 * 4 * 64 * 8 * 2;
  short* w2f   = (short*)ws;                        ws += 2 * 8 * 64 * 8 * 2;
  short* w4f   = (short*)ws;                        ws += 2 * 8 * 64 * 8 * 2;
  short* wa1f  = (short*)ws;                        ws += 4 * 8 * 64 * 8 * 2;
  short* wa2f  = (short*)ws;                        ws += 4 * 8 * 64 * 8 * 2;
  short* wp1f  = (short*)ws;                        ws += 4 * 16 * 64 * 8 * 2;
  short* wp2f  = (short*)ws;                        ws += 4 * 16 * 64 * 8 * 2;
  short* wff   = (short*)ws;                        ws += 16 * 32 * 64 * 8 * 2;

  k_prep<<<dim3(744 + 512), dim3(64), 0, stream>>>(
      w1, w3, w2, w4, a1_att, a2_att, a1_w, a2_w, wf,
      w1f, w3f, w2f, w4f, wa1f, wa2f, wp1f, wp2f, wff,
      x, lw, ls, lb, h, xx);

  k_knn<<<dim3(256), dim3(256), 0, stream>>>(h, xx, knn_idx);
  k_branch_all<<<dim3(BB * NN / 8, 2), dim3(512), 0, stream>>>(
      h, knn_idx,
      w1f, s1, b1, w2f, s2, b2, wa1f,
      w3f, s3, b3, w4f, s4, b4, wa2f, fbuf);
  k_att<<<dim3(BB * NN / 64, 2), dim3(256), 0, stream>>>(
      fbuf, wp1f, a1_s, a1_b, wp2f, a2_s, a2_b);
  k_final<<<dim3(8, 128), dim3(256), 0, stream>>>(fbuf, wff, sf, bf, out);
}

// Round 14
// 261.831 us; speedup vs baseline: 1.2044x; 1.2044x over previous
//
#include <hip/hip_runtime.h>
#include <hip/hip_bf16.h>
#include <math.h>

#define BB 16
#define NN 2048

typedef short bf16x8 __attribute__((ext_vector_type(8)));
typedef float f32x4 __attribute__((ext_vector_type(4)));
typedef unsigned long long u64;

#define MFMA(a, b, c) __builtin_amdgcn_mfma_f32_16x16x32_bf16(a, b, c, 0, 0, 0)

static __device__ __forceinline__ short f2bf(float f) {
  union { float f; unsigned u; } v; v.f = f;
  unsigned r = v.u + 0x7fffu + ((v.u >> 16) & 1u);
  return (short)(r >> 16);
}
static __device__ __forceinline__ short f2bf_hw(float f) {
  unsigned u;
  asm("v_cvt_pk_bf16_f32 %0, %1, %1" : "=v"(u) : "v"(f));
  return (short)u;
}
static __device__ __forceinline__ unsigned f2bf2(float lo, float hi) {
  unsigned u;
  asm("v_cvt_pk_bf16_f32 %0, %1, %2" : "=v"(u) : "v"(lo), "v"(hi));
  return u;
}

// ---------------- K0: fused weight-pack (BN scale folded) + h/xx compute ----------------
__global__ __launch_bounds__(64) void k_prep(
    const float* __restrict__ w1, const float* __restrict__ s1,
    const float* __restrict__ w3, const float* __restrict__ s3,
    const float* __restrict__ w2, const float* __restrict__ s2,
    const float* __restrict__ w4, const float* __restrict__ s4,
    const float* __restrict__ a1_att, const float* __restrict__ a2_att,
    const float* __restrict__ a1_w, const float* __restrict__ a1s,
    const float* __restrict__ a2_w, const float* __restrict__ a2s,
    const float* __restrict__ wf, const float* __restrict__ sf,
    short* __restrict__ w1f, short* __restrict__ w3f,
    short* __restrict__ w2f, short* __restrict__ w4f,
    short* __restrict__ wa1f, short* __restrict__ wa2f,
    short* __restrict__ wp1f, short* __restrict__ wp2f,
    short* __restrict__ wff,
    const float* __restrict__ x, const float* __restrict__ lw,
    const float* __restrict__ ls, const float* __restrict__ lb,
    float* __restrict__ h, float* __restrict__ xx) {
  int bb = blockIdx.x;
  if (bb >= 744) {
    int p = (bb - 744) * 64 + threadIdx.x;
    int b = p >> 11;
    int n = p & (NN - 1);
    const float* xb = x + (size_t)b * 3 * NN + n;
    float x0 = xb[0], x1 = xb[NN], x2 = xb[2 * NN];
    float hv[8];
    float ss = 0.f;
#pragma unroll
    for (int o = 0; o < 8; ++o) {
      float v = x0 * lw[o * 3 + 0] + x1 * lw[o * 3 + 1] + x2 * lw[o * 3 + 2];
      v = fmaxf(v * ls[o] + lb[o], 0.f);
      hv[o] = v;
      ss += v * v;  // same order as k_knn inner product -> self-dist exactly 0
    }
    float4* hp = (float4*)(h + (size_t)p * 8);
    hp[0] = make_float4(hv[0], hv[1], hv[2], hv[3]);
    hp[1] = make_float4(hv[4], hv[5], hv[6], hv[7]);
    xx[p] = ss;
    return;
  }
  const float* src;
  const float* scl;
  short* dst;
  int O, C, base;
  if (bb < 4)        { src = w1;     scl = s1;  dst = w1f;  O = 64;  C = 16;  base = 0; }
  else if (bb < 8)   { src = w3;     scl = s3;  dst = w3f;  O = 64;  C = 16;  base = 4; }
  else if (bb < 24)  { src = w2;     scl = s2;  dst = w2f;  O = 128; C = 64;  base = 8; }
  else if (bb < 40)  { src = w4;     scl = s4;  dst = w4f;  O = 128; C = 64;  base = 24; }
  else if (bb < 72)  { src = a1_att; scl = 0;   dst = wa1f; O = 128; C = 128; base = 40; }
  else if (bb < 104) { src = a2_att; scl = 0;   dst = wa2f; O = 128; C = 128; base = 72; }
  else if (bb < 168) { src = a1_w;   scl = a1s; dst = wp1f; O = 256; C = 128; base = 104; }
  else if (bb < 232) { src = a2_w;   scl = a2s; dst = wp2f; O = 256; C = 128; base = 168; }
  else               { src = wf;     scl = sf;  dst = wff;  O = 512; C = 512; base = 232; }
  int blk = bb - base;
  int NCT = O >> 4;
  int ct = blk % NCT;
  int kt = blk / NCT;
  int l = threadIdx.x;
  int col = ct * 16 + (l & 15);
  float sc = scl ? scl[col] : 1.f;
  bf16x8 v;
#pragma unroll
  for (int i = 0; i < 8; ++i) {
    int k = kt * 32 + ((l >> 4) << 3) + i;
    v[i] = (k < C) ? f2bf(src[(size_t)col * C + k] * sc) : (short)0;
  }
  ((bf16x8*)dst)[(size_t)blk * 64 + l] = v;
}

// ---------------- K2: kNN top-16. Scalar-pipe candidate reads (wave-uniform s_load) ------
// r12 shape: 512 blocks x 8 waves, 1 query/lane, wave slice = 256 candidates. Candidate
// vectors are wave-uniform -> readfirstlane'd indices compile to s_load into SGPRs; the
// FMA takes the SGPR operand directly. Zero LDS in the scan; LDS only for thr + stacks +
// merge (33 KB). Distance expr/order/keys/tie-order byte-identical to r12 -> exact.
__global__ __launch_bounds__(512, 4) void k_knn(const float* __restrict__ h,
                                                const float* __restrict__ xx,
                                                int* __restrict__ knn_idx) {
  __shared__ __align__(16) unsigned char smem[33024];
  unsigned* thr = (unsigned*)smem;             // [64]
  u64* stkb = (u64*)(smem + 256);              // [512][8] u64 = 32768; merge overlays this

  int tid = threadIdx.x;
  int lane = tid & 63;
  int w = __builtin_amdgcn_readfirstlane(tid >> 6);   // provably wave-uniform
  int blk = blockIdx.x;
  int b = blk >> 5;
  int qloc = ((blk & 31) << 6) + lane;
  int p = (b << 11) + qloc;
  const float* hb = h + ((size_t)b << 11) * 8;
  const float* xxb = xx + ((size_t)b << 11);

  float4 q0 = *(const float4*)(hb + (size_t)qloc * 8);
  float4 q1 = *(const float4*)(hb + (size_t)qloc * 8 + 4);
  float xq = xxb[qloc];

  if (tid < 64) thr[tid] = 0x007FFFFFu;
  __syncthreads();

  u64* stkrow = stkb + tid * 8;
  u64 a[16];
#pragma unroll
  for (int i = 0; i < 16; ++i) a[i] = 0ULL;
  int cnt = 0;

  auto innerm = [&](int m) -> float {   // m wave-uniform -> scalar loads
    float4 a0 = *(const float4*)(hb + (size_t)m * 8);
    float4 a1 = *(const float4*)(hb + (size_t)m * 8 + 4);
    return q0.x * a0.x + q0.y * a0.y + q0.z * a0.z + q0.w * a0.w +
           q1.x * a1.x + q1.y * a1.y + q1.z * a1.z + q1.w * a1.w;
  };
  auto mkkey = [&](float d, int mg) -> u64 {
    unsigned uu = __float_as_uint(d);
    unsigned key = ((int)uu >= 0) ? (uu | 0x80000000u) : ~uu;
    return ((u64)key << 32) | (unsigned)(NN - 1 - mg);
  };
  auto decode = [&](unsigned t32) -> float {
    unsigned tu = (t32 & 0x80000000u) ? (t32 & 0x7fffffffu) : ~t32;
    return __uint_as_float(tu);
  };

  auto flush = [&]() {
    u64 c[8];
#pragma unroll
    for (int j = 0; j < 8; ++j) {
      u64 v = stkrow[j];
      c[j] = (j < cnt) ? v : 0ULL;
    }
    cnt = 0;
#pragma unroll
    for (int k = 2; k <= 8; k <<= 1)
#pragma unroll
      for (int j = k >> 1; j > 0; j >>= 1)
#pragma unroll
        for (int i = 0; i < 8; ++i) {
          int l = i ^ j;
          if (l > i) {
            bool up = ((i & k) == 0);
            u64 xi = c[i], xl = c[l];
            bool sw = up ? (xi > xl) : (xi < xl);
            if (sw) { c[i] = xl; c[l] = xi; }
          }
        }
    u64 m[16];
#pragma unroll
    for (int i = 0; i < 16; ++i) {
      u64 bi = (i < 8) ? c[7 - i] : 0ULL;
      m[i] = (a[i] > bi) ? a[i] : bi;
    }
#pragma unroll
    for (int j = 8; j > 0; j >>= 1)
#pragma unroll
      for (int i = 0; i < 16; ++i) {
        int l = i ^ j;
        if (l > i && m[i] > m[l]) { u64 t = m[i]; m[i] = m[l]; m[l] = t; }
      }
#pragma unroll
    for (int i = 0; i < 16; ++i) a[i] = m[i];
  };

  int sbase = w * 256;
  // warm start: exact sort of the first 16 candidates of this wave's slice
  {
    u64 cc[16];
#pragma unroll
    for (int j = 0; j < 16; ++j)
      cc[j] = mkkey(2.f * innerm(sbase + j) - xq - xxb[sbase + j], sbase + j);
#pragma unroll
    for (int k = 2; k <= 16; k <<= 1)
#pragma unroll
      for (int j = k >> 1; j > 0; j >>= 1)
#pragma unroll
        for (int i = 0; i < 16; ++i) {
          int l = i ^ j;
          if (l > i) {
            bool up = ((i & k) == 0);
            u64 xi = cc[i], xl = cc[l];
            bool sw = up ? (xi > xl) : (xi < xl);
            if (sw) { cc[i] = xl; cc[l] = xi; }
          }
        }
#pragma unroll
    for (int i = 0; i < 16; ++i) a[i] = cc[i];
    atomicMax(&thr[lane], (unsigned)(a[0] >> 32));
  }

  for (int s16 = 16; s16 < 256; s16 += 16) {
    float thrF = decode(thr[lane]);
#pragma unroll 1
    for (int s4 = 0; s4 < 16; s4 += 4) {
      int m0 = sbase + s16 + s4;
      float4 xm4 = *(const float4*)(xxb + m0);   // uniform, 16B-aligned
#pragma unroll
      for (int u = 0; u < 4; ++u) {
        float xm = (u == 0) ? xm4.x : (u == 1) ? xm4.y : (u == 2) ? xm4.z : xm4.w;
        float d = 2.f * innerm(m0 + u) - xq - xm;
        if (d >= thrF) { stkrow[cnt] = mkkey(d, m0 + u); cnt++; }
      }
      if (__any(cnt >= 5)) {
        flush();
        atomicMax(&thr[lane], (unsigned)(a[0] >> 32));
        thrF = decode(thr[lane]);
      }
    }
  }
  if (__any(cnt > 0)) flush();

  // ---- merge tree: 8 lists/query -> 1, in the (now dead) stack region, stride 16 ----
  u64* M = (u64*)(smem + 256);   // rows [r][16]

  auto mergeLds = [&](const u64* src) {
    u64 m[16];
#pragma unroll
    for (int i = 0; i < 16; ++i) {
      u64 bi = src[15 - i];
      m[i] = (a[i] > bi) ? a[i] : bi;
    }
#pragma unroll
    for (int j = 8; j > 0; j >>= 1)
#pragma unroll
      for (int i = 0; i < 16; ++i) {
        int l = i ^ j;
        if (l > i && m[i] > m[l]) { u64 t = m[i]; m[i] = m[l]; m[l] = t; }
      }
#pragma unroll
    for (int i = 0; i < 16; ++i) a[i] = m[i];
  };

  __syncthreads();
  if (w >= 4) {
#pragma unroll
    for (int i = 0; i < 16; ++i) M[((w - 4) * 64 + lane) * 16 + i] = a[i];
  }
  __syncthreads();
  if (w < 4) mergeLds(&M[(w * 64 + lane) * 16]);
  __syncthreads();
  if (w == 2 || w == 3) {
#pragma unroll
    for (int i = 0; i < 16; ++i) M[((w - 2) * 64 + lane) * 16 + i] = a[i];
  }
  __syncthreads();
  if (w < 2) mergeLds(&M[(w * 64 + lane) * 16]);
  __syncthreads();
  if (w == 1) {
#pragma unroll
    for (int i = 0; i < 16; ++i) M[lane * 16 + i] = a[i];
  }
  __syncthreads();
  if (w == 0) {
    mergeLds(&M[lane * 16]);
    int ids[16];
#pragma unroll
    for (int r = 0; r < 16; ++r)
      ids[r] = (NN - 1) - (int)(unsigned)(a[15 - r] & 0xFFFFFFFFULL);
    int4* op = (int4*)(knn_idx + (size_t)p * 16);
    op[0] = make_int4(ids[0], ids[1], ids[2], ids[3]);
    op[1] = make_int4(ids[4], ids[5], ids[6], ids[7]);
    op[2] = make_int4(ids[8], ids[9], ids[10], ids[11]);
    op[3] = make_int4(ids[12], ids[13], ids[14], ids[15]);
  }
}

// ---------------- K3: edge->conv1->conv2->att-score->pool (BN scale pre-folded) ----------
__global__ __launch_bounds__(512, 6) void k_branch_all(
    const float* __restrict__ h, const int* __restrict__ knn_idx,
    const short* __restrict__ w1f, const float* __restrict__ b1,
    const short* __restrict__ w2f, const float* __restrict__ b2,
    const short* __restrict__ wa1f,
    const short* __restrict__ w3f, const float* __restrict__ b3,
    const short* __restrict__ w4f, const float* __restrict__ b4,
    const short* __restrict__ wa2f,
    short* __restrict__ fout) {
  __shared__ __align__(16) unsigned char smem[53248];
  short (*e_s)[40]  = (short(*)[40])smem;              // [128][40], phases A-B only
  short (*g2_s)[136] = (short(*)[136])smem;            // [128][136], phases C-D (overlays e_s)
  short (*g1_s)[72] = (short(*)[72])(smem + 34816);    // [128][72]

  int br = blockIdx.y;
  const short* W1 = br ? w3f : w1f;
  const float* B1 = br ? b3 : b1;
  const short* W2 = br ? w4f : w2f;
  const float* B2 = br ? b4 : b2;
  const short* WA = br ? wa2f : wa1f;
  int KR = br ? 12 : 16;
  int FOFF = br ? 256 : 0;

  int tid = threadIdx.x;
  int lane = tid & 63;
  int w = tid >> 6;
  int lr = lane & 15;
  int lg = lane >> 4;
  int pbase = blockIdx.x * 8;
  const float* hb = h + ((size_t)(pbase & ~(NN - 1))) * 8;

  // Phase A: edge features
  if (tid < 128) {
    int t = tid >> 4, j = tid & 15;
    int p = pbase + t;
    const float* cp = h + (size_t)p * 8;
    bool real = (j < KR);
    unsigned d0 = 0, d1 = 0, d2 = 0, d3 = 0, c0 = 0, c1 = 0, c2 = 0, c3 = 0;
    if (real) {
      int id = knn_idx[(size_t)p * 16 + j];
      const float* np_ = hb + (size_t)id * 8;
      float cv0 = cp[0], cv1 = cp[1], cv2 = cp[2], cv3 = cp[3];
      float cv4 = cp[4], cv5 = cp[5], cv6 = cp[6], cv7 = cp[7];
      d0 = f2bf2(np_[0] - cv0, np_[1] - cv1);
      d1 = f2bf2(np_[2] - cv2, np_[3] - cv3);
      d2 = f2bf2(np_[4] - cv4, np_[5] - cv5);
      d3 = f2bf2(np_[6] - cv6, np_[7] - cv7);
      c0 = f2bf2(cv0, cv1); c1 = f2bf2(cv2, cv3);
      c2 = f2bf2(cv4, cv5); c3 = f2bf2(cv6, cv7);
    }
    *(uint4*)&e_s[tid][0] = make_uint4(d0, d1, d2, d3);
    *(uint4*)&e_s[tid][8] = make_uint4(c0, c1, c2, c3);
    *(uint4*)&e_s[tid][16] = make_uint4(0, 0, 0, 0);
    *(uint4*)&e_s[tid][24] = make_uint4(0, 0, 0, 0);
  }
  __syncthreads();

  // Phase B: conv1 16->64 (scale folded into W1)
  {
    int ct = w & 3;
    int rhalf = w >> 2;
    int o = ct * 16 + lr;
    bf16x8 bfrag = ((const bf16x8*)W1)[ct * 64 + lane];
    float bia = B1[o];
#pragma unroll
    for (int rt = 0; rt < 4; ++rt) {
      int rr = rhalf * 4 + rt;
      bf16x8 af = *(const bf16x8*)&e_s[rr * 16 + lr][lg * 8];
      f32x4 acc = {0.f, 0.f, 0.f, 0.f};
      acc = MFMA(af, bfrag, acc);
#pragma unroll
      for (int q = 0; q < 4; ++q) {
        g1_s[rr * 16 + lg * 4 + q][o] = f2bf_hw(fmaxf(acc[q] + bia, 0.f));
      }
    }
  }
  __syncthreads();  // e_s dead; bytes become g2_s

  // Phase C: conv2 64->128 (scale folded into W2)
  float g2r[8][4];
  {
    int ct = w;
    int o = ct * 16 + lr;
    bf16x8 bf0 = ((const bf16x8*)W2)[(0 * 8 + ct) * 64 + lane];
    bf16x8 bf1 = ((const bf16x8*)W2)[(1 * 8 + ct) * 64 + lane];
    float bia = B2[o];
#pragma unroll
    for (int rt = 0; rt < 8; ++rt) {
      bf16x8 a0 = *(const bf16x8*)&g1_s[rt * 16 + lr][lg * 8];
      bf16x8 a1 = *(const bf16x8*)&g1_s[rt * 16 + lr][32 + lg * 8];
      f32x4 acc = {0.f, 0.f, 0.f, 0.f};
      acc = MFMA(a0, bf0, acc);
      acc = MFMA(a1, bf1, acc);
#pragma unroll
      for (int q = 0; q < 4; ++q) {
        float v = fmaxf(acc[q] + bia, 0.f);
        g2r[rt][q] = v;
        g2_s[rt * 16 + lg * 4 + q][o] = f2bf_hw(v);
      }
    }
  }
  __syncthreads();

  // Phase D: att score (sigmoid)*g2, masked k-sum -> fbuf[p][FOFF..FOFF+128)
  {
    int ct = w;
    int o = ct * 16 + lr;
    bf16x8 bfr[4];
#pragma unroll
    for (int kt = 0; kt < 4; ++kt) bfr[kt] = ((const bf16x8*)WA)[(kt * 8 + ct) * 64 + lane];
#pragma unroll
    for (int rt = 0; rt < 8; ++rt) {
      f32x4 acc = {0.f, 0.f, 0.f, 0.f};
#pragma unroll
      for (int kt = 0; kt < 4; ++kt) {
        bf16x8 a = *(const bf16x8*)&g2_s[rt * 16 + lr][kt * 32 + lg * 8];
        acc = MFMA(a, bfr[kt], acc);
      }
      float v = 0.f;
#pragma unroll
      for (int q = 0; q < 4; ++q) {
        int jj = lg * 4 + q;
        float sg = __builtin_amdgcn_rcpf(1.f + __expf(-acc[q]));
        if (jj < KR) v += g2r[rt][q] * sg;
      }
      v += __shfl_xor(v, 16);
      v += __shfl_xor(v, 32);
      if (lane < 16)
        fout[(size_t)(pbase + rt) * 512 + FOFF + o] = f2bf_hw(v);
    }
  }
}

// ---------------- K3b: att conv 128->256 per branch, IN-PLACE on fbuf (scale folded) ----
__global__ __launch_bounds__(256, 4) void k_att(
    short* __restrict__ fb,
    const short* __restrict__ wp1f, const float* __restrict__ a1b,
    const short* __restrict__ wp2f, const float* __restrict__ a2b) {
  __shared__ short ptile[64][136];
  int br = blockIdx.y;
  const short* WP = br ? wp2f : wp1f;
  const float* BP = br ? a2b : a1b;
  int FOFF = br ? 256 : 0;

  int tid = threadIdx.x;
  int lane = tid & 63;
  int w = tid >> 6;
  int lr = lane & 15;
  int lg = lane >> 4;
  int p0 = blockIdx.x * 64;

#pragma unroll
  for (int i = 0; i < 4; ++i) {
    int f = i * 256 + tid;
    int row = f >> 4, seg = f & 15;
    *(float4*)&ptile[row][seg * 8] =
        *(const float4*)(fb + (size_t)(p0 + row) * 512 + FOFF + seg * 8);
  }
  __syncthreads();

  bf16x8 af[4][4];
#pragma unroll
  for (int rt = 0; rt < 4; ++rt)
#pragma unroll
    for (int kt = 0; kt < 4; ++kt)
      af[rt][kt] = *(const bf16x8*)&ptile[rt * 16 + lr][kt * 32 + lg * 8];

#pragma unroll
  for (int cc = 0; cc < 4; ++cc) {
    int ct = w * 4 + cc;
    int o = ct * 16 + lr;
    bf16x8 bfr[4];
#pragma unroll
    for (int kt = 0; kt < 4; ++kt) bfr[kt] = ((const bf16x8*)WP)[(kt * 16 + ct) * 64 + lane];
    float bia = BP[o];
#pragma unroll
    for (int rt = 0; rt < 4; ++rt) {
      f32x4 acc = {0.f, 0.f, 0.f, 0.f};
#pragma unroll
      for (int kt = 0; kt < 4; ++kt) acc = MFMA(af[rt][kt], bfr[kt], acc);
#pragma unroll
      for (int q = 0; q < 4; ++q) {
        float v = fmaxf(acc[q] + bia, 0.f);
        fb[(size_t)(p0 + rt * 16 + lg * 4 + q) * 512 + FOFF + o] = f2bf_hw(v);
      }
    }
  }
}

// ---------------- K4: out = relu(f @ (wf*sf)^T + bf) computed transposed ----------------
__global__ __launch_bounds__(256, 4) void k_final(
    const short* __restrict__ fbuf, const short* __restrict__ wff,
    const float* __restrict__ bfv, float* __restrict__ out) {
  __shared__ short b_s[256][72];
  int tid = threadIdx.x;
  int lane = tid & 63;
  int w = tid >> 6;
  int lr = lane & 15;
  int lg = lane >> 4;
  int ob = blockIdx.x;
  int p0 = blockIdx.y * 256;
  int rtg = ob * 4 + w;

  f32x4 acc[16];
#pragma unroll
  for (int ct = 0; ct < 16; ++ct) acc[ct] = (f32x4){0.f, 0.f, 0.f, 0.f};

  for (int kc = 0; kc < 512; kc += 64) {
    __syncthreads();
#pragma unroll
    for (int c = 0; c < 8; ++c) {
      int idx = c * 256 + tid;
      int row = idx >> 3, seg = idx & 7;
      *(float4*)&b_s[row][seg * 8] =
          *(const float4*)(fbuf + ((size_t)(p0 + row) * 512 + kc + seg * 8));
    }
    __syncthreads();
    int kt = kc >> 5;
    bf16x8 a0 = ((const bf16x8*)wff)[((size_t)(kt + 0) * 32 + rtg) * 64 + lane];
    bf16x8 a1 = ((const bf16x8*)wff)[((size_t)(kt + 1) * 32 + rtg) * 64 + lane];
#pragma unroll
    for (int ct = 0; ct < 16; ++ct) {
      bf16x8 bb0 = *(const bf16x8*)&b_s[ct * 16 + lr][lg * 8];
      bf16x8 bb1 = *(const bf16x8*)&b_s[ct * 16 + lr][32 + lg * 8];
      acc[ct] = MFMA(a0, bb0, acc[ct]);
      acc[ct] = MFMA(a1, bb1, acc[ct]);
    }
  }

  int b = p0 >> 11;
  int nb = p0 & (NN - 1);
#pragma unroll
  for (int q = 0; q < 4; ++q) {
    int o = rtg * 16 + lg * 4 + q;
    float bia = bfv[o];
#pragma unroll
    for (int ct = 0; ct < 16; ++ct) {
      int n = nb + ct * 16 + lr;
      float v = fmaxf(acc[ct][q] + bia, 0.f);
      out[((size_t)b * 512 + o) * NN + n] = v;
    }
  }
}

extern "C" void kernel_launch(void* const* d_in, const int* in_sizes, int n_in,
                              void* d_out, int out_size, void* d_ws, size_t ws_size,
                              hipStream_t stream) {
  const float* x      = (const float*)d_in[0];
  const float* lw     = (const float*)d_in[1];
  const float* ls     = (const float*)d_in[2];
  const float* lb     = (const float*)d_in[3];
  const float* w1     = (const float*)d_in[4];
  const float* s1     = (const float*)d_in[5];
  const float* b1     = (const float*)d_in[6];
  const float* w2     = (const float*)d_in[7];
  const float* s2     = (const float*)d_in[8];
  const float* b2     = (const float*)d_in[9];
  const float* w3     = (const float*)d_in[10];
  const float* s3     = (const float*)d_in[11];
  const float* b3     = (const float*)d_in[12];
  const float* w4     = (const float*)d_in[13];
  const float* s4     = (const float*)d_in[14];
  const float* b4     = (const float*)d_in[15];
  const float* a1_att = (const float*)d_in[16];
  const float* a1_w   = (const float*)d_in[17];
  const float* a1_s   = (const float*)d_in[18];
  const float* a1_b   = (const float*)d_in[19];
  const float* a2_att = (const float*)d_in[20];
  const float* a2_w   = (const float*)d_in[21];
  const float* a2_s   = (const float*)d_in[22];
  const float* a2_b   = (const float*)d_in[23];
  const float* wf     = (const float*)d_in[24];
  const float* sf     = (const float*)d_in[25];
  const float* bf     = (const float*)d_in[26];
  float* out = (float*)d_out;

  char* ws = (char*)d_ws;
  float* h   = (float*)ws;                          ws += (size_t)BB * NN * 8 * 4;
  float* xx  = (float*)ws;                          ws += (size_t)BB * NN * 4;
  int* knn_idx = (int*)ws;                          ws += (size_t)BB * NN * 16 * 4;
  short* fbuf  = (short*)ws;                        ws += (size_t)BB * NN * 512 * 2;
  short* w1f   = (short*)ws;                        ws += 1 * 4 * 64 * 8 * 2;
  short* w3f   = (short*)ws;                        ws += 1 * 4 * 64 * 8 * 2;
  short* w2f   = (short*)ws;                        ws += 2 * 8 * 64 * 8 * 2;
  short* w4f   = (short*)ws;                        ws += 2 * 8 * 64 * 8 * 2;
  short* wa1f  = (short*)ws;                        ws += 4 * 8 * 64 * 8 * 2;
  short* wa2f  = (short*)ws;                        ws += 4 * 8 * 64 * 8 * 2;
  short* wp1f  = (short*)ws;                        ws += 4 * 16 * 64 * 8 * 2;
  short* wp2f  = (short*)ws;                        ws += 4 * 16 * 64 * 8 * 2;
  short* wff   = (short*)ws;                        ws += 16 * 32 * 64 * 8 * 2;

  k_prep<<<dim3(744 + 512), dim3(64), 0, stream>>>(
      w1, s1, w3, s3, w2, s2, w4, s4, a1_att, a2_att,
      a1_w, a1_s, a2_w, a2_s, wf, sf,
      w1f, w3f, w2f, w4f, wa1f, wa2f, wp1f, wp2f, wff,
      x, lw, ls, lb, h, xx);

  k_knn<<<dim3(512), dim3(512), 0, stream>>>(h, xx, knn_idx);
  k_branch_all<<<dim3(BB * NN / 8, 2), dim3(512), 0, stream>>>(
      h, knn_idx,
      w1f, b1, w2f, b2, wa1f,
      w3f, b3, w4f, b4, wa2f, fbuf);
  k_att<<<dim3(BB * NN / 64, 2), dim3(256), 0, stream>>>(
      fbuf, wp1f, a1_b, wp2f, a2_b);
  k_final<<<dim3(8, 128), dim3(256), 0, stream>>>(fbuf, wff, bf, out);
}

// Round 15
// 243.622 us; speedup vs baseline: 1.2944x; 1.0747x over previous
//
#include <hip/hip_runtime.h>
#include <hip/hip_bf16.h>
#include <math.h>

#define BB 16
#define NN 2048

typedef short bf16x8 __attribute__((ext_vector_type(8)));
typedef float f32x4 __attribute__((ext_vector_type(4)));
typedef unsigned long long u64;

#define MFMA(a, b, c) __builtin_amdgcn_mfma_f32_16x16x32_bf16(a, b, c, 0, 0, 0)

static __device__ __forceinline__ short f2bf(float f) {
  union { float f; unsigned u; } v; v.f = f;
  unsigned r = v.u + 0x7fffu + ((v.u >> 16) & 1u);
  return (short)(r >> 16);
}
static __device__ __forceinline__ short f2bf_hw(float f) {
  unsigned u;
  asm("v_cvt_pk_bf16_f32 %0, %1, %1" : "=v"(u) : "v"(f));
  return (short)u;
}
static __device__ __forceinline__ unsigned f2bf2(float lo, float hi) {
  unsigned u;
  asm("v_cvt_pk_bf16_f32 %0, %1, %2" : "=v"(u) : "v"(lo), "v"(hi));
  return u;
}

// ---------------- K0: fused weight-pack (BN scale folded) + h/xx compute ----------------
__global__ __launch_bounds__(64) void k_prep(
    const float* __restrict__ w1, const float* __restrict__ s1,
    const float* __restrict__ w3, const float* __restrict__ s3,
    const float* __restrict__ w2, const float* __restrict__ s2,
    const float* __restrict__ w4, const float* __restrict__ s4,
    const float* __restrict__ a1_att, const float* __restrict__ a2_att,
    const float* __restrict__ a1_w, const float* __restrict__ a1s,
    const float* __restrict__ a2_w, const float* __restrict__ a2s,
    const float* __restrict__ wf, const float* __restrict__ sf,
    short* __restrict__ w1f, short* __restrict__ w3f,
    short* __restrict__ w2f, short* __restrict__ w4f,
    short* __restrict__ wa1f, short* __restrict__ wa2f,
    short* __restrict__ wp1f, short* __restrict__ wp2f,
    short* __restrict__ wff,
    const float* __restrict__ x, const float* __restrict__ lw,
    const float* __restrict__ ls, const float* __restrict__ lb,
    float* __restrict__ h, float* __restrict__ xx) {
  int bb = blockIdx.x;
  if (bb >= 744) {
    int p = (bb - 744) * 64 + threadIdx.x;
    int b = p >> 11;
    int n = p & (NN - 1);
    const float* xb = x + (size_t)b * 3 * NN + n;
    float x0 = xb[0], x1 = xb[NN], x2 = xb[2 * NN];
    float hv[8];
    float ss = 0.f;
#pragma unroll
    for (int o = 0; o < 8; ++o) {
      float v = x0 * lw[o * 3 + 0] + x1 * lw[o * 3 + 1] + x2 * lw[o * 3 + 2];
      v = fmaxf(v * ls[o] + lb[o], 0.f);
      hv[o] = v;
      ss += v * v;  // same order as k_knn inner product -> self-dist exactly 0
    }
    float4* hp = (float4*)(h + (size_t)p * 8);
    hp[0] = make_float4(hv[0], hv[1], hv[2], hv[3]);
    hp[1] = make_float4(hv[4], hv[5], hv[6], hv[7]);
    xx[p] = ss;
    return;
  }
  const float* src;
  const float* scl;
  short* dst;
  int O, C, base;
  if (bb < 4)        { src = w1;     scl = s1;  dst = w1f;  O = 64;  C = 16;  base = 0; }
  else if (bb < 8)   { src = w3;     scl = s3;  dst = w3f;  O = 64;  C = 16;  base = 4; }
  else if (bb < 24)  { src = w2;     scl = s2;  dst = w2f;  O = 128; C = 64;  base = 8; }
  else if (bb < 40)  { src = w4;     scl = s4;  dst = w4f;  O = 128; C = 64;  base = 24; }
  else if (bb < 72)  { src = a1_att; scl = 0;   dst = wa1f; O = 128; C = 128; base = 40; }
  else if (bb < 104) { src = a2_att; scl = 0;   dst = wa2f; O = 128; C = 128; base = 72; }
  else if (bb < 168) { src = a1_w;   scl = a1s; dst = wp1f; O = 256; C = 128; base = 104; }
  else if (bb < 232) { src = a2_w;   scl = a2s; dst = wp2f; O = 256; C = 128; base = 168; }
  else               { src = wf;     scl = sf;  dst = wff;  O = 512; C = 512; base = 232; }
  int blk = bb - base;
  int NCT = O >> 4;
  int ct = blk % NCT;
  int kt = blk / NCT;
  int l = threadIdx.x;
  int col = ct * 16 + (l & 15);
  float sc = scl ? scl[col] : 1.f;
  bf16x8 v;
#pragma unroll
  for (int i = 0; i < 8; ++i) {
    int k = kt * 32 + ((l >> 4) << 3) + i;
    v[i] = (k < C) ? f2bf(src[(size_t)col * C + k] * sc) : (short)0;
  }
  ((bf16x8*)dst)[(size_t)blk * 64 + l] = v;
}

// ---------------- K2: kNN top-16 (r12 proven version: LDS staging, shared thresholds) ----
__global__ __launch_bounds__(512, 4) void k_knn(const float* __restrict__ h,
                                                const float* __restrict__ xx,
                                                int* __restrict__ knn_idx) {
  __shared__ __align__(16) unsigned char smem[52224];
  float4* sh4 = (float4*)smem;
  float* sxx = (float*)(smem + 16384);
  unsigned* thr = (unsigned*)(smem + 18432);
  u64* stkb = (u64*)(smem + 18688);

  int tid = threadIdx.x;
  int lane = tid & 63;
  int w = tid >> 6;
  int blk = blockIdx.x;
  int b = blk >> 5;
  int qloc = ((blk & 31) << 6) + lane;
  int p = (b << 11) + qloc;
  const float* hb = h + ((size_t)b << 11) * 8;
  const float* xxb = xx + ((size_t)b << 11);

  const float4* qp = (const float4*)(hb + (size_t)qloc * 8);
  float4 q0 = qp[0], q1 = qp[1];
  float xq = xxb[qloc];

  if (tid < 64) thr[tid] = 0x007FFFFFu;
  __syncthreads();

  u64* stkrow = stkb + tid * 8;
  u64 a[16];
#pragma unroll
  for (int i = 0; i < 16; ++i) a[i] = 0ULL;
  int cnt = 0;

  auto inner8 = [&](int s) -> float {
    float4 a0 = sh4[(w * 64 + s) * 2 + 0];
    float4 a1 = sh4[(w * 64 + s) * 2 + 1];
    return q0.x * a0.x + q0.y * a0.y + q0.z * a0.z + q0.w * a0.w +
           q1.x * a1.x + q1.y * a1.y + q1.z * a1.z + q1.w * a1.w;
  };
  auto mkkey = [&](float d, int mg) -> u64 {
    unsigned uu = __float_as_uint(d);
    unsigned key = ((int)uu >= 0) ? (uu | 0x80000000u) : ~uu;
    return ((u64)key << 32) | (unsigned)(NN - 1 - mg);
  };

  auto flush = [&]() {
    u64 c[8];
#pragma unroll
    for (int j = 0; j < 8; ++j) {
      u64 v = stkrow[j];
      c[j] = (j < cnt) ? v : 0ULL;
    }
    cnt = 0;
#pragma unroll
    for (int k = 2; k <= 8; k <<= 1)
#pragma unroll
      for (int j = k >> 1; j > 0; j >>= 1)
#pragma unroll
        for (int i = 0; i < 8; ++i) {
          int l = i ^ j;
          if (l > i) {
            bool up = ((i & k) == 0);
            u64 xi = c[i], xl = c[l];
            bool sw = up ? (xi > xl) : (xi < xl);
            if (sw) { c[i] = xl; c[l] = xi; }
          }
        }
    u64 m[16];
#pragma unroll
    for (int i = 0; i < 16; ++i) {
      u64 bi = (i < 8) ? c[7 - i] : 0ULL;
      m[i] = (a[i] > bi) ? a[i] : bi;
    }
#pragma unroll
    for (int j = 8; j > 0; j >>= 1)
#pragma unroll
      for (int i = 0; i < 16; ++i) {
        int l = i ^ j;
        if (l > i && m[i] > m[l]) { u64 t = m[i]; m[i] = m[l]; m[l] = t; }
      }
#pragma unroll
    for (int i = 0; i < 16; ++i) a[i] = m[i];
  };

  int sbase = w * 256;
  float4 r0, r1;
  float rx;
  {
    const float* cp = hb + (size_t)(sbase + lane) * 8;
    r0 = *(const float4*)cp;
    r1 = *(const float4*)(cp + 4);
    rx = xxb[sbase + lane];
  }
  for (int c2 = 0; c2 < 4; ++c2) {
    sh4[(w * 64 + lane) * 2 + 0] = r0;
    sh4[(w * 64 + lane) * 2 + 1] = r1;
    sxx[w * 64 + lane] = rx;
    if (c2 < 3) {
      const float* cp = hb + (size_t)(sbase + (c2 + 1) * 64 + lane) * 8;
      r0 = *(const float4*)cp;
      r1 = *(const float4*)(cp + 4);
      rx = xxb[sbase + (c2 + 1) * 64 + lane];
    }
    int mg0 = sbase + c2 * 64;
    int sstart = 0;
    if (c2 == 0) {
      u64 cc[16];
#pragma unroll
      for (int j = 0; j < 16; ++j) cc[j] = mkkey(2.f * inner8(j) - xq - sxx[w * 64 + j], mg0 + j);
#pragma unroll
      for (int k = 2; k <= 16; k <<= 1)
#pragma unroll
        for (int j = k >> 1; j > 0; j >>= 1)
#pragma unroll
          for (int i = 0; i < 16; ++i) {
            int l = i ^ j;
            if (l > i) {
              bool up = ((i & k) == 0);
              u64 xi = cc[i], xl = cc[l];
              bool sw = up ? (xi > xl) : (xi < xl);
              if (sw) { cc[i] = xl; cc[l] = xi; }
            }
          }
#pragma unroll
      for (int i = 0; i < 16; ++i) a[i] = cc[i];
      atomicMax(&thr[lane], (unsigned)(a[0] >> 32));
      sstart = 16;
    }
    for (int s16 = sstart; s16 < 64; s16 += 16) {
      unsigned t32 = thr[lane];
      unsigned tu = (t32 & 0x80000000u) ? (t32 & 0x7fffffffu) : ~t32;
      float thrF = __uint_as_float(tu);
#pragma unroll
      for (int s4 = 0; s4 < 16; s4 += 4) {
        int s = s16 + s4;
        float4 xm4 = *(const float4*)&sxx[w * 64 + s];
#pragma unroll
        for (int u = 0; u < 4; ++u) {
          float xm = (u == 0) ? xm4.x : (u == 1) ? xm4.y : (u == 2) ? xm4.z : xm4.w;
          float d = 2.f * inner8(s + u) - xq - xm;
          if (d >= thrF) { stkrow[cnt] = mkkey(d, mg0 + s + u); cnt++; }
        }
        if (__any(cnt >= 5)) {
          flush();
          atomicMax(&thr[lane], (unsigned)(a[0] >> 32));
          unsigned t2 = thr[lane];
          unsigned tu2 = (t2 & 0x80000000u) ? (t2 & 0x7fffffffu) : ~t2;
          thrF = __uint_as_float(tu2);
        }
      }
    }
  }
  if (__any(cnt > 0)) flush();

  u64* M1 = (u64*)smem;
  u64* M2 = (u64*)(smem + 34816);
  u64* M3 = (u64*)smem;

  auto mergeLds = [&](const u64* src) {
    u64 m[16];
#pragma unroll
    for (int i = 0; i < 16; ++i) {
      u64 bi = src[15 - i];
      m[i] = (a[i] > bi) ? a[i] : bi;
    }
#pragma unroll
    for (int j = 8; j > 0; j >>= 1)
#pragma unroll
      for (int i = 0; i < 16; ++i) {
        int l = i ^ j;
        if (l > i && m[i] > m[l]) { u64 t = m[i]; m[i] = m[l]; m[l] = t; }
      }
#pragma unroll
    for (int i = 0; i < 16; ++i) a[i] = m[i];
  };

  __syncthreads();
  if (w >= 4) {
#pragma unroll
    for (int i = 0; i < 16; ++i) M1[((w - 4) * 64 + lane) * 17 + i] = a[i];
  }
  __syncthreads();
  if (w < 4) mergeLds(&M1[(w * 64 + lane) * 17]);
  __syncthreads();
  if (w == 2 || w == 3) {
#pragma unroll
    for (int i = 0; i < 16; ++i) M2[((w - 2) * 64 + lane) * 17 + i] = a[i];
  }
  __syncthreads();
  if (w < 2) mergeLds(&M2[(w * 64 + lane) * 17]);
  __syncthreads();
  if (w == 1) {
#pragma unroll
    for (int i = 0; i < 16; ++i) M3[lane * 17 + i] = a[i];
  }
  __syncthreads();
  if (w == 0) {
    mergeLds(&M3[lane * 17]);
    int ids[16];
#pragma unroll
    for (int r = 0; r < 16; ++r)
      ids[r] = (NN - 1) - (int)(unsigned)(a[15 - r] & 0xFFFFFFFFULL);
    int4* op = (int4*)(knn_idx + (size_t)p * 16);
    op[0] = make_int4(ids[0], ids[1], ids[2], ids[3]);
    op[1] = make_int4(ids[4], ids[5], ids[6], ids[7]);
    op[2] = make_int4(ids[8], ids[9], ids[10], ids[11]);
    op[3] = make_int4(ids[12], ids[13], ids[14], ids[15]);
  }
}

// ---------------- K3: edge->conv1->conv2->att-score->pool (BN scale pre-folded) ----------
__global__ __launch_bounds__(512, 6) void k_branch_all(
    const float* __restrict__ h, const int* __restrict__ knn_idx,
    const short* __restrict__ w1f, const float* __restrict__ b1,
    const short* __restrict__ w2f, const float* __restrict__ b2,
    const short* __restrict__ wa1f,
    const short* __restrict__ w3f, const float* __restrict__ b3,
    const short* __restrict__ w4f, const float* __restrict__ b4,
    const short* __restrict__ wa2f,
    short* __restrict__ fout) {
  __shared__ __align__(16) unsigned char smem[53248];
  short (*e_s)[40]  = (short(*)[40])smem;              // [128][40], phases A-B only
  short (*g2_s)[136] = (short(*)[136])smem;            // [128][136], phases C-D (overlays e_s)
  short (*g1_s)[72] = (short(*)[72])(smem + 34816);    // [128][72]

  int br = blockIdx.y;
  const short* W1 = br ? w3f : w1f;
  const float* B1 = br ? b3 : b1;
  const short* W2 = br ? w4f : w2f;
  const float* B2 = br ? b4 : b2;
  const short* WA = br ? wa2f : wa1f;
  int KR = br ? 12 : 16;
  int FOFF = br ? 256 : 0;

  int tid = threadIdx.x;
  int lane = tid & 63;
  int w = tid >> 6;
  int lr = lane & 15;
  int lg = lane >> 4;
  int pbase = blockIdx.x * 8;
  const float* hb = h + ((size_t)(pbase & ~(NN - 1))) * 8;

  // Phase A: edge features
  if (tid < 128) {
    int t = tid >> 4, j = tid & 15;
    int p = pbase + t;
    const float* cp = h + (size_t)p * 8;
    bool real = (j < KR);
    unsigned d0 = 0, d1 = 0, d2 = 0, d3 = 0, c0 = 0, c1 = 0, c2 = 0, c3 = 0;
    if (real) {
      int id = knn_idx[(size_t)p * 16 + j];
      const float* np_ = hb + (size_t)id * 8;
      float cv0 = cp[0], cv1 = cp[1], cv2 = cp[2], cv3 = cp[3];
      float cv4 = cp[4], cv5 = cp[5], cv6 = cp[6], cv7 = cp[7];
      d0 = f2bf2(np_[0] - cv0, np_[1] - cv1);
      d1 = f2bf2(np_[2] - cv2, np_[3] - cv3);
      d2 = f2bf2(np_[4] - cv4, np_[5] - cv5);
      d3 = f2bf2(np_[6] - cv6, np_[7] - cv7);
      c0 = f2bf2(cv0, cv1); c1 = f2bf2(cv2, cv3);
      c2 = f2bf2(cv4, cv5); c3 = f2bf2(cv6, cv7);
    }
    *(uint4*)&e_s[tid][0] = make_uint4(d0, d1, d2, d3);
    *(uint4*)&e_s[tid][8] = make_uint4(c0, c1, c2, c3);
    *(uint4*)&e_s[tid][16] = make_uint4(0, 0, 0, 0);
    *(uint4*)&e_s[tid][24] = make_uint4(0, 0, 0, 0);
  }
  __syncthreads();

  // Phase B: conv1 16->64 (scale folded into W1)
  {
    int ct = w & 3;
    int rhalf = w >> 2;
    int o = ct * 16 + lr;
    bf16x8 bfrag = ((const bf16x8*)W1)[ct * 64 + lane];
    float bia = B1[o];
#pragma unroll
    for (int rt = 0; rt < 4; ++rt) {
      int rr = rhalf * 4 + rt;
      bf16x8 af = *(const bf16x8*)&e_s[rr * 16 + lr][lg * 8];
      f32x4 acc = {0.f, 0.f, 0.f, 0.f};
      acc = MFMA(af, bfrag, acc);
#pragma unroll
      for (int q = 0; q < 4; ++q) {
        g1_s[rr * 16 + lg * 4 + q][o] = f2bf_hw(fmaxf(acc[q] + bia, 0.f));
      }
    }
  }
  __syncthreads();  // e_s dead; bytes become g2_s

  // Phase C: conv2 64->128 (scale folded into W2)
  float g2r[8][4];
  {
    int ct = w;
    int o = ct * 16 + lr;
    bf16x8 bf0 = ((const bf16x8*)W2)[(0 * 8 + ct) * 64 + lane];
    bf16x8 bf1 = ((const bf16x8*)W2)[(1 * 8 + ct) * 64 + lane];
    float bia = B2[o];
#pragma unroll
    for (int rt = 0; rt < 8; ++rt) {
      bf16x8 a0 = *(const bf16x8*)&g1_s[rt * 16 + lr][lg * 8];
      bf16x8 a1 = *(const bf16x8*)&g1_s[rt * 16 + lr][32 + lg * 8];
      f32x4 acc = {0.f, 0.f, 0.f, 0.f};
      acc = MFMA(a0, bf0, acc);
      acc = MFMA(a1, bf1, acc);
#pragma unroll
      for (int q = 0; q < 4; ++q) {
        float v = fmaxf(acc[q] + bia, 0.f);
        g2r[rt][q] = v;
        g2_s[rt * 16 + lg * 4 + q][o] = f2bf_hw(v);
      }
    }
  }
  __syncthreads();

  // Phase D: att score (sigmoid)*g2, masked k-sum -> fbuf[p][FOFF..FOFF+128)
  {
    int ct = w;
    int o = ct * 16 + lr;
    bf16x8 bfr[4];
#pragma unroll
    for (int kt = 0; kt < 4; ++kt) bfr[kt] = ((const bf16x8*)WA)[(kt * 8 + ct) * 64 + lane];
#pragma unroll
    for (int rt = 0; rt < 8; ++rt) {
      f32x4 acc = {0.f, 0.f, 0.f, 0.f};
#pragma unroll
      for (int kt = 0; kt < 4; ++kt) {
        bf16x8 a = *(const bf16x8*)&g2_s[rt * 16 + lr][kt * 32 + lg * 8];
        acc = MFMA(a, bfr[kt], acc);
      }
      float v = 0.f;
#pragma unroll
      for (int q = 0; q < 4; ++q) {
        int jj = lg * 4 + q;
        float sg = __builtin_amdgcn_rcpf(1.f + __expf(-acc[q]));
        if (jj < KR) v += g2r[rt][q] * sg;
      }
      v += __shfl_xor(v, 16);
      v += __shfl_xor(v, 32);
      if (lane < 16)
        fout[(size_t)(pbase + rt) * 512 + FOFF + o] = f2bf_hw(v);
    }
  }
}

// ---------------- K3b: att conv 128->256 per branch, IN-PLACE on fbuf (scale folded) ----
__global__ __launch_bounds__(256, 4) void k_att(
    short* __restrict__ fb,
    const short* __restrict__ wp1f, const float* __restrict__ a1b,
    const short* __restrict__ wp2f, const float* __restrict__ a2b) {
  __shared__ short ptile[64][136];
  int br = blockIdx.y;
  const short* WP = br ? wp2f : wp1f;
  const float* BP = br ? a2b : a1b;
  int FOFF = br ? 256 : 0;

  int tid = threadIdx.x;
  int lane = tid & 63;
  int w = tid >> 6;
  int lr = lane & 15;
  int lg = lane >> 4;
  int p0 = blockIdx.x * 64;

#pragma unroll
  for (int i = 0; i < 4; ++i) {
    int f = i * 256 + tid;
    int row = f >> 4, seg = f & 15;
    *(float4*)&ptile[row][seg * 8] =
        *(const float4*)(fb + (size_t)(p0 + row) * 512 + FOFF + seg * 8);
  }
  __syncthreads();

  bf16x8 af[4][4];
#pragma unroll
  for (int rt = 0; rt < 4; ++rt)
#pragma unroll
    for (int kt = 0; kt < 4; ++kt)
      af[rt][kt] = *(const bf16x8*)&ptile[rt * 16 + lr][kt * 32 + lg * 8];

#pragma unroll
  for (int cc = 0; cc < 4; ++cc) {
    int ct = w * 4 + cc;
    int o = ct * 16 + lr;
    bf16x8 bfr[4];
#pragma unroll
    for (int kt = 0; kt < 4; ++kt) bfr[kt] = ((const bf16x8*)WP)[(kt * 16 + ct) * 64 + lane];
    float bia = BP[o];
#pragma unroll
    for (int rt = 0; rt < 4; ++rt) {
      f32x4 acc = {0.f, 0.f, 0.f, 0.f};
#pragma unroll
      for (int kt = 0; kt < 4; ++kt) acc = MFMA(af[rt][kt], bfr[kt], acc);
#pragma unroll
      for (int q = 0; q < 4; ++q) {
        float v = fmaxf(acc[q] + bia, 0.f);
        fb[(size_t)(p0 + rt * 16 + lg * 4 + q) * 512 + FOFF + o] = f2bf_hw(v);
      }
    }
  }
}

// ---------------- K4: out = relu(f @ (wf*sf)^T + bf) computed transposed ----------------
__global__ __launch_bounds__(256, 4) void k_final(
    const short* __restrict__ fbuf, const short* __restrict__ wff,
    const float* __restrict__ bfv, float* __restrict__ out) {
  __shared__ short b_s[256][72];
  int tid = threadIdx.x;
  int lane = tid & 63;
  int w = tid >> 6;
  int lr = lane & 15;
  int lg = lane >> 4;
  int ob = blockIdx.x;
  int p0 = blockIdx.y * 256;
  int rtg = ob * 4 + w;

  f32x4 acc[16];
#pragma unroll
  for (int ct = 0; ct < 16; ++ct) acc[ct] = (f32x4){0.f, 0.f, 0.f, 0.f};

  for (int kc = 0; kc < 512; kc += 64) {
    __syncthreads();
#pragma unroll
    for (int c = 0; c < 8; ++c) {
      int idx = c * 256 + tid;
      int row = idx >> 3, seg = idx & 7;
      *(float4*)&b_s[row][seg * 8] =
          *(const float4*)(fbuf + ((size_t)(p0 + row) * 512 + kc + seg * 8));
    }
    __syncthreads();
    int kt = kc >> 5;
    bf16x8 a0 = ((const bf16x8*)wff)[((size_t)(kt + 0) * 32 + rtg) * 64 + lane];
    bf16x8 a1 = ((const bf16x8*)wff)[((size_t)(kt + 1) * 32 + rtg) * 64 + lane];
#pragma unroll
    for (int ct = 0; ct < 16; ++ct) {
      bf16x8 bb0 = *(const bf16x8*)&b_s[ct * 16 + lr][lg * 8];
      bf16x8 bb1 = *(const bf16x8*)&b_s[ct * 16 + lr][32 + lg * 8];
      acc[ct] = MFMA(a0, bb0, acc[ct]);
      acc[ct] = MFMA(a1, bb1, acc[ct]);
    }
  }

  int b = p0 >> 11;
  int nb = p0 & (NN - 1);
#pragma unroll
  for (int q = 0; q < 4; ++q) {
    int o = rtg * 16 + lg * 4 + q;
    float bia = bfv[o];
#pragma unroll
    for (int ct = 0; ct < 16; ++ct) {
      int n = nb + ct * 16 + lr;
      float v = fmaxf(acc[ct][q] + bia, 0.f);
      out[((size_t)b * 512 + o) * NN + n] = v;
    }
  }
}

extern "C" void kernel_launch(void* const* d_in, const int* in_sizes, int n_in,
                              void* d_out, int out_size, void* d_ws, size_t ws_size,
                              hipStream_t stream) {
  const float* x      = (const float*)d_in[0];
  const float* lw     = (const float*)d_in[1];
  const float* ls     = (const float*)d_in[2];
  const float* lb     = (const float*)d_in[3];
  const float* w1     = (const float*)d_in[4];
  const float* s1     = (const float*)d_in[5];
  const float* b1     = (const float*)d_in[6];
  const float* w2     = (const float*)d_in[7];
  const float* s2     = (const float*)d_in[8];
  const float* b2     = (const float*)d_in[9];
  const float* w3     = (const float*)d_in[10];
  const float* s3     = (const float*)d_in[11];
  const float* b3     = (const float*)d_in[12];
  const float* w4     = (const float*)d_in[13];
  const float* s4     = (const float*)d_in[14];
  const float* b4     = (const float*)d_in[15];
  const float* a1_att = (const float*)d_in[16];
  const float* a1_w   = (const float*)d_in[17];
  const float* a1_s   = (const float*)d_in[18];
  const float* a1_b   = (const float*)d_in[19];
  const float* a2_att = (const float*)d_in[20];
  const float* a2_w   = (const float*)d_in[21];
  const float* a2_s   = (const float*)d_in[22];
  const float* a2_b   = (const float*)d_in[23];
  const float* wf     = (const float*)d_in[24];
  const float* sf     = (const float*)d_in[25];
  const float* bf     = (const float*)d_in[26];
  float* out = (float*)d_out;

  char* ws = (char*)d_ws;
  float* h   = (float*)ws;                          ws += (size_t)BB * NN * 8 * 4;
  float* xx  = (float*)ws;                          ws += (size_t)BB * NN * 4;
  int* knn_idx = (int*)ws;                          ws += (size_t)BB * NN * 16 * 4;
  short* fbuf  = (short*)ws;                        ws += (size_t)BB * NN * 512 * 2;
  short* w1f   = (short*)ws;                        ws += 1 * 4 * 64 * 8 * 2;
  short* w3f   = (short*)ws;                        ws += 1 * 4 * 64 * 8 * 2;
  short* w2f   = (short*)ws;                        ws += 2 * 8 * 64 * 8 * 2;
  short* w4f   = (short*)ws;                        ws += 2 * 8 * 64 * 8 * 2;
  short* wa1f  = (short*)ws;                        ws += 4 * 8 * 64 * 8 * 2;
  short* wa2f  = (short*)ws;                        ws += 4 * 8 * 64 * 8 * 2;
  short* wp1f  = (short*)ws;                        ws += 4 * 16 * 64 * 8 * 2;
  short* wp2f  = (short*)ws;                        ws += 4 * 16 * 64 * 8 * 2;
  short* wff   = (short*)ws;                        ws += 16 * 32 * 64 * 8 * 2;

  k_prep<<<dim3(744 + 512), dim3(64), 0, stream>>>(
      w1, s1, w3, s3, w2, s2, w4, s4, a1_att, a2_att,
      a1_w, a1_s, a2_w, a2_s, wf, sf,
      w1f, w3f, w2f, w4f, wa1f, wa2f, wp1f, wp2f, wff,
      x, lw, ls, lb, h, xx);

  k_knn<<<dim3(512), dim3(512), 0, stream>>>(h, xx, knn_idx);
  k_branch_all<<<dim3(BB * NN / 8, 2), dim3(512), 0, stream>>>(
      h, knn_idx,
      w1f, b1, w2f, b2, wa1f,
      w3f, b3, w4f, b4, wa2f, fbuf);
  k_att<<<dim3(BB * NN / 64, 2), dim3(256), 0, stream>>>(
      fbuf, wp1f, a1_b, wp2f, a2_b);
  k_final<<<dim3(8, 128), dim3(256), 0, stream>>>(fbuf, wff, bf, out);
}

// Round 16
// 242.963 us; speedup vs baseline: 1.2979x; 1.0027x over previous
//
#include <hip/hip_runtime.h>
#include <hip/hip_bf16.h>
#include <math.h>

#define BB 16
#define NN 2048

typedef short bf16x8 __attribute__((ext_vector_type(8)));
typedef float f32x4 __attribute__((ext_vector_type(4)));
typedef unsigned long long u64;

#define MFMA(a, b, c) __builtin_amdgcn_mfma_f32_16x16x32_bf16(a, b, c, 0, 0, 0)

static __device__ __forceinline__ short f2bf(float f) {
  union { float f; unsigned u; } v; v.f = f;
  unsigned r = v.u + 0x7fffu + ((v.u >> 16) & 1u);
  return (short)(r >> 16);
}
static __device__ __forceinline__ short f2bf_hw(float f) {
  unsigned u;
  asm("v_cvt_pk_bf16_f32 %0, %1, %1" : "=v"(u) : "v"(f));
  return (short)u;
}
static __device__ __forceinline__ unsigned f2bf2(float lo, float hi) {
  unsigned u;
  asm("v_cvt_pk_bf16_f32 %0, %1, %2" : "=v"(u) : "v"(lo), "v"(hi));
  return u;
}
static __device__ __forceinline__ void gload16(const void* g, void* l) {
  __builtin_amdgcn_global_load_lds(
      (const __attribute__((address_space(1))) void*)g,
      (__attribute__((address_space(3))) void*)l, 16, 0, 0);
}

// ---------------- K0: fused weight-pack (BN scale folded) + h/xx compute ----------------
__global__ __launch_bounds__(64) void k_prep(
    const float* __restrict__ w1, const float* __restrict__ s1,
    const float* __restrict__ w3, const float* __restrict__ s3,
    const float* __restrict__ w2, const float* __restrict__ s2,
    const float* __restrict__ w4, const float* __restrict__ s4,
    const float* __restrict__ a1_att, const float* __restrict__ a2_att,
    const float* __restrict__ a1_w, const float* __restrict__ a1s,
    const float* __restrict__ a2_w, const float* __restrict__ a2s,
    const float* __restrict__ wf, const float* __restrict__ sf,
    short* __restrict__ w1f, short* __restrict__ w3f,
    short* __restrict__ w2f, short* __restrict__ w4f,
    short* __restrict__ wa1f, short* __restrict__ wa2f,
    short* __restrict__ wp1f, short* __restrict__ wp2f,
    short* __restrict__ wff,
    const float* __restrict__ x, const float* __restrict__ lw,
    const float* __restrict__ ls, const float* __restrict__ lb,
    float* __restrict__ h, float* __restrict__ xx) {
  int bb = blockIdx.x;
  if (bb >= 744) {
    int p = (bb - 744) * 64 + threadIdx.x;
    int b = p >> 11;
    int n = p & (NN - 1);
    const float* xb = x + (size_t)b * 3 * NN + n;
    float x0 = xb[0], x1 = xb[NN], x2 = xb[2 * NN];
    float hv[8];
    float ss = 0.f;
#pragma unroll
    for (int o = 0; o < 8; ++o) {
      float v = x0 * lw[o * 3 + 0] + x1 * lw[o * 3 + 1] + x2 * lw[o * 3 + 2];
      v = fmaxf(v * ls[o] + lb[o], 0.f);
      hv[o] = v;
      ss += v * v;  // same order as k_knn inner product -> self-dist exactly 0
    }
    float4* hp = (float4*)(h + (size_t)p * 8);
    hp[0] = make_float4(hv[0], hv[1], hv[2], hv[3]);
    hp[1] = make_float4(hv[4], hv[5], hv[6], hv[7]);
    xx[p] = ss;
    return;
  }
  const float* src;
  const float* scl;
  short* dst;
  int O, C, base;
  if (bb < 4)        { src = w1;     scl = s1;  dst = w1f;  O = 64;  C = 16;  base = 0; }
  else if (bb < 8)   { src = w3;     scl = s3;  dst = w3f;  O = 64;  C = 16;  base = 4; }
  else if (bb < 24)  { src = w2;     scl = s2;  dst = w2f;  O = 128; C = 64;  base = 8; }
  else if (bb < 40)  { src = w4;     scl = s4;  dst = w4f;  O = 128; C = 64;  base = 24; }
  else if (bb < 72)  { src = a1_att; scl = 0;   dst = wa1f; O = 128; C = 128; base = 40; }
  else if (bb < 104) { src = a2_att; scl = 0;   dst = wa2f; O = 128; C = 128; base = 72; }
  else if (bb < 168) { src = a1_w;   scl = a1s; dst = wp1f; O = 256; C = 128; base = 104; }
  else if (bb < 232) { src = a2_w;   scl = a2s; dst = wp2f; O = 256; C = 128; base = 168; }
  else               { src = wf;     scl = sf;  dst = wff;  O = 512; C = 512; base = 232; }
  int blk = bb - base;
  int NCT = O >> 4;
  int ct = blk % NCT;
  int kt = blk / NCT;
  int l = threadIdx.x;
  int col = ct * 16 + (l & 15);
  float sc = scl ? scl[col] : 1.f;
  bf16x8 v;
#pragma unroll
  for (int i = 0; i < 8; ++i) {
    int k = kt * 32 + ((l >> 4) << 3) + i;
    v[i] = (k < C) ? f2bf(src[(size_t)col * C + k] * sc) : (short)0;
  }
  ((bf16x8*)dst)[(size_t)blk * 64 + l] = v;
}

// ---------------- K2: kNN top-16 (r12 proven version: LDS staging, shared thresholds) ----
__global__ __launch_bounds__(512, 4) void k_knn(const float* __restrict__ h,
                                                const float* __restrict__ xx,
                                                int* __restrict__ knn_idx) {
  __shared__ __align__(16) unsigned char smem[52224];
  float4* sh4 = (float4*)smem;
  float* sxx = (float*)(smem + 16384);
  unsigned* thr = (unsigned*)(smem + 18432);
  u64* stkb = (u64*)(smem + 18688);

  int tid = threadIdx.x;
  int lane = tid & 63;
  int w = tid >> 6;
  int blk = blockIdx.x;
  int b = blk >> 5;
  int qloc = ((blk & 31) << 6) + lane;
  int p = (b << 11) + qloc;
  const float* hb = h + ((size_t)b << 11) * 8;
  const float* xxb = xx + ((size_t)b << 11);

  const float4* qp = (const float4*)(hb + (size_t)qloc * 8);
  float4 q0 = qp[0], q1 = qp[1];
  float xq = xxb[qloc];

  if (tid < 64) thr[tid] = 0x007FFFFFu;
  __syncthreads();

  u64* stkrow = stkb + tid * 8;
  u64 a[16];
#pragma unroll
  for (int i = 0; i < 16; ++i) a[i] = 0ULL;
  int cnt = 0;

  auto inner8 = [&](int s) -> float {
    float4 a0 = sh4[(w * 64 + s) * 2 + 0];
    float4 a1 = sh4[(w * 64 + s) * 2 + 1];
    return q0.x * a0.x + q0.y * a0.y + q0.z * a0.z + q0.w * a0.w +
           q1.x * a1.x + q1.y * a1.y + q1.z * a1.z + q1.w * a1.w;
  };
  auto mkkey = [&](float d, int mg) -> u64 {
    unsigned uu = __float_as_uint(d);
    unsigned key = ((int)uu >= 0) ? (uu | 0x80000000u) : ~uu;
    return ((u64)key << 32) | (unsigned)(NN - 1 - mg);
  };

  auto flush = [&]() {
    u64 c[8];
#pragma unroll
    for (int j = 0; j < 8; ++j) {
      u64 v = stkrow[j];
      c[j] = (j < cnt) ? v : 0ULL;
    }
    cnt = 0;
#pragma unroll
    for (int k = 2; k <= 8; k <<= 1)
#pragma unroll
      for (int j = k >> 1; j > 0; j >>= 1)
#pragma unroll
        for (int i = 0; i < 8; ++i) {
          int l = i ^ j;
          if (l > i) {
            bool up = ((i & k) == 0);
            u64 xi = c[i], xl = c[l];
            bool sw = up ? (xi > xl) : (xi < xl);
            if (sw) { c[i] = xl; c[l] = xi; }
          }
        }
    u64 m[16];
#pragma unroll
    for (int i = 0; i < 16; ++i) {
      u64 bi = (i < 8) ? c[7 - i] : 0ULL;
      m[i] = (a[i] > bi) ? a[i] : bi;
    }
#pragma unroll
    for (int j = 8; j > 0; j >>= 1)
#pragma unroll
      for (int i = 0; i < 16; ++i) {
        int l = i ^ j;
        if (l > i && m[i] > m[l]) { u64 t = m[i]; m[i] = m[l]; m[l] = t; }
      }
#pragma unroll
    for (int i = 0; i < 16; ++i) a[i] = m[i];
  };

  int sbase = w * 256;
  float4 r0, r1;
  float rx;
  {
    const float* cp = hb + (size_t)(sbase + lane) * 8;
    r0 = *(const float4*)cp;
    r1 = *(const float4*)(cp + 4);
    rx = xxb[sbase + lane];
  }
  for (int c2 = 0; c2 < 4; ++c2) {
    sh4[(w * 64 + lane) * 2 + 0] = r0;
    sh4[(w * 64 + lane) * 2 + 1] = r1;
    sxx[w * 64 + lane] = rx;
    if (c2 < 3) {
      const float* cp = hb + (size_t)(sbase + (c2 + 1) * 64 + lane) * 8;
      r0 = *(const float4*)cp;
      r1 = *(const float4*)(cp + 4);
      rx = xxb[sbase + (c2 + 1) * 64 + lane];
    }
    int mg0 = sbase + c2 * 64;
    int sstart = 0;
    if (c2 == 0) {
      u64 cc[16];
#pragma unroll
      for (int j = 0; j < 16; ++j) cc[j] = mkkey(2.f * inner8(j) - xq - sxx[w * 64 + j], mg0 + j);
#pragma unroll
      for (int k = 2; k <= 16; k <<= 1)
#pragma unroll
        for (int j = k >> 1; j > 0; j >>= 1)
#pragma unroll
          for (int i = 0; i < 16; ++i) {
            int l = i ^ j;
            if (l > i) {
              bool up = ((i & k) == 0);
              u64 xi = cc[i], xl = cc[l];
              bool sw = up ? (xi > xl) : (xi < xl);
              if (sw) { cc[i] = xl; cc[l] = xi; }
            }
          }
#pragma unroll
      for (int i = 0; i < 16; ++i) a[i] = cc[i];
      atomicMax(&thr[lane], (unsigned)(a[0] >> 32));
      sstart = 16;
    }
    for (int s16 = sstart; s16 < 64; s16 += 16) {
      unsigned t32 = thr[lane];
      unsigned tu = (t32 & 0x80000000u) ? (t32 & 0x7fffffffu) : ~t32;
      float thrF = __uint_as_float(tu);
#pragma unroll
      for (int s4 = 0; s4 < 16; s4 += 4) {
        int s = s16 + s4;
        float4 xm4 = *(const float4*)&sxx[w * 64 + s];
#pragma unroll
        for (int u = 0; u < 4; ++u) {
          float xm = (u == 0) ? xm4.x : (u == 1) ? xm4.y : (u == 2) ? xm4.z : xm4.w;
          float d = 2.f * inner8(s + u) - xq - xm;
          if (d >= thrF) { stkrow[cnt] = mkkey(d, mg0 + s + u); cnt++; }
        }
        if (__any(cnt >= 5)) {
          flush();
          atomicMax(&thr[lane], (unsigned)(a[0] >> 32));
          unsigned t2 = thr[lane];
          unsigned tu2 = (t2 & 0x80000000u) ? (t2 & 0x7fffffffu) : ~t2;
          thrF = __uint_as_float(tu2);
        }
      }
    }
  }
  if (__any(cnt > 0)) flush();

  u64* M1 = (u64*)smem;
  u64* M2 = (u64*)(smem + 34816);
  u64* M3 = (u64*)smem;

  auto mergeLds = [&](const u64* src) {
    u64 m[16];
#pragma unroll
    for (int i = 0; i < 16; ++i) {
      u64 bi = src[15 - i];
      m[i] = (a[i] > bi) ? a[i] : bi;
    }
#pragma unroll
    for (int j = 8; j > 0; j >>= 1)
#pragma unroll
      for (int i = 0; i < 16; ++i) {
        int l = i ^ j;
        if (l > i && m[i] > m[l]) { u64 t = m[i]; m[i] = m[l]; m[l] = t; }
      }
#pragma unroll
    for (int i = 0; i < 16; ++i) a[i] = m[i];
  };

  __syncthreads();
  if (w >= 4) {
#pragma unroll
    for (int i = 0; i < 16; ++i) M1[((w - 4) * 64 + lane) * 17 + i] = a[i];
  }
  __syncthreads();
  if (w < 4) mergeLds(&M1[(w * 64 + lane) * 17]);
  __syncthreads();
  if (w == 2 || w == 3) {
#pragma unroll
    for (int i = 0; i < 16; ++i) M2[((w - 2) * 64 + lane) * 17 + i] = a[i];
  }
  __syncthreads();
  if (w < 2) mergeLds(&M2[(w * 64 + lane) * 17]);
  __syncthreads();
  if (w == 1) {
#pragma unroll
    for (int i = 0; i < 16; ++i) M3[lane * 17 + i] = a[i];
  }
  __syncthreads();
  if (w == 0) {
    mergeLds(&M3[lane * 17]);
    int ids[16];
#pragma unroll
    for (int r = 0; r < 16; ++r)
      ids[r] = (NN - 1) - (int)(unsigned)(a[15 - r] & 0xFFFFFFFFULL);
    int4* op = (int4*)(knn_idx + (size_t)p * 16);
    op[0] = make_int4(ids[0], ids[1], ids[2], ids[3]);
    op[1] = make_int4(ids[4], ids[5], ids[6], ids[7]);
    op[2] = make_int4(ids[8], ids[9], ids[10], ids[11]);
    op[3] = make_int4(ids[12], ids[13], ids[14], ids[15]);
  }
}

// ---------------- K3: edge->conv1->conv2->att-score->pool (BN scale pre-folded) ----------
__global__ __launch_bounds__(512, 6) void k_branch_all(
    const float* __restrict__ h, const int* __restrict__ knn_idx,
    const short* __restrict__ w1f, const float* __restrict__ b1,
    const short* __restrict__ w2f, const float* __restrict__ b2,
    const short* __restrict__ wa1f,
    const short* __restrict__ w3f, const float* __restrict__ b3,
    const short* __restrict__ w4f, const float* __restrict__ b4,
    const short* __restrict__ wa2f,
    short* __restrict__ fout) {
  __shared__ __align__(16) unsigned char smem[53248];
  short (*e_s)[40]  = (short(*)[40])smem;              // [128][40], phases A-B only
  short (*g2_s)[136] = (short(*)[136])smem;            // [128][136], phases C-D (overlays e_s)
  short (*g1_s)[72] = (short(*)[72])(smem + 34816);    // [128][72]

  int br = blockIdx.y;
  const short* W1 = br ? w3f : w1f;
  const float* B1 = br ? b3 : b1;
  const short* W2 = br ? w4f : w2f;
  const float* B2 = br ? b4 : b2;
  const short* WA = br ? wa2f : wa1f;
  int KR = br ? 12 : 16;
  int FOFF = br ? 256 : 0;

  int tid = threadIdx.x;
  int lane = tid & 63;
  int w = tid >> 6;
  int lr = lane & 15;
  int lg = lane >> 4;
  int pbase = blockIdx.x * 8;
  const float* hb = h + ((size_t)(pbase & ~(NN - 1))) * 8;

  // Phase A: edge features
  if (tid < 128) {
    int t = tid >> 4, j = tid & 15;
    int p = pbase + t;
    const float* cp = h + (size_t)p * 8;
    bool real = (j < KR);
    unsigned d0 = 0, d1 = 0, d2 = 0, d3 = 0, c0 = 0, c1 = 0, c2 = 0, c3 = 0;
    if (real) {
      int id = knn_idx[(size_t)p * 16 + j];
      const float* np_ = hb + (size_t)id * 8;
      float cv0 = cp[0], cv1 = cp[1], cv2 = cp[2], cv3 = cp[3];
      float cv4 = cp[4], cv5 = cp[5], cv6 = cp[6], cv7 = cp[7];
      d0 = f2bf2(np_[0] - cv0, np_[1] - cv1);
      d1 = f2bf2(np_[2] - cv2, np_[3] - cv3);
      d2 = f2bf2(np_[4] - cv4, np_[5] - cv5);
      d3 = f2bf2(np_[6] - cv6, np_[7] - cv7);
      c0 = f2bf2(cv0, cv1); c1 = f2bf2(cv2, cv3);
      c2 = f2bf2(cv4, cv5); c3 = f2bf2(cv6, cv7);
    }
    *(uint4*)&e_s[tid][0] = make_uint4(d0, d1, d2, d3);
    *(uint4*)&e_s[tid][8] = make_uint4(c0, c1, c2, c3);
    *(uint4*)&e_s[tid][16] = make_uint4(0, 0, 0, 0);
    *(uint4*)&e_s[tid][24] = make_uint4(0, 0, 0, 0);
  }
  __syncthreads();

  // Phase B: conv1 16->64 (scale folded into W1)
  {
    int ct = w & 3;
    int rhalf = w >> 2;
    int o = ct * 16 + lr;
    bf16x8 bfrag = ((const bf16x8*)W1)[ct * 64 + lane];
    float bia = B1[o];
#pragma unroll
    for (int rt = 0; rt < 4; ++rt) {
      int rr = rhalf * 4 + rt;
      bf16x8 af = *(const bf16x8*)&e_s[rr * 16 + lr][lg * 8];
      f32x4 acc = {0.f, 0.f, 0.f, 0.f};
      acc = MFMA(af, bfrag, acc);
#pragma unroll
      for (int q = 0; q < 4; ++q) {
        g1_s[rr * 16 + lg * 4 + q][o] = f2bf_hw(fmaxf(acc[q] + bia, 0.f));
      }
    }
  }
  __syncthreads();  // e_s dead; bytes become g2_s

  // Phase C: conv2 64->128 (scale folded into W2)
  float g2r[8][4];
  {
    int ct = w;
    int o = ct * 16 + lr;
    bf16x8 bf0 = ((const bf16x8*)W2)[(0 * 8 + ct) * 64 + lane];
    bf16x8 bf1 = ((const bf16x8*)W2)[(1 * 8 + ct) * 64 + lane];
    float bia = B2[o];
#pragma unroll
    for (int rt = 0; rt < 8; ++rt) {
      bf16x8 a0 = *(const bf16x8*)&g1_s[rt * 16 + lr][lg * 8];
      bf16x8 a1 = *(const bf16x8*)&g1_s[rt * 16 + lr][32 + lg * 8];
      f32x4 acc = {0.f, 0.f, 0.f, 0.f};
      acc = MFMA(a0, bf0, acc);
      acc = MFMA(a1, bf1, acc);
#pragma unroll
      for (int q = 0; q < 4; ++q) {
        float v = fmaxf(acc[q] + bia, 0.f);
        g2r[rt][q] = v;
        g2_s[rt * 16 + lg * 4 + q][o] = f2bf_hw(v);
      }
    }
  }
  __syncthreads();

  // Phase D: att score (sigmoid)*g2, masked k-sum -> fbuf[p][FOFF..FOFF+128)
  {
    int ct = w;
    int o = ct * 16 + lr;
    bf16x8 bfr[4];
#pragma unroll
    for (int kt = 0; kt < 4; ++kt) bfr[kt] = ((const bf16x8*)WA)[(kt * 8 + ct) * 64 + lane];
#pragma unroll
    for (int rt = 0; rt < 8; ++rt) {
      f32x4 acc = {0.f, 0.f, 0.f, 0.f};
#pragma unroll
      for (int kt = 0; kt < 4; ++kt) {
        bf16x8 a = *(const bf16x8*)&g2_s[rt * 16 + lr][kt * 32 + lg * 8];
        acc = MFMA(a, bfr[kt], acc);
      }
      float v = 0.f;
#pragma unroll
      for (int q = 0; q < 4; ++q) {
        int jj = lg * 4 + q;
        float sg = __builtin_amdgcn_rcpf(1.f + __expf(-acc[q]));
        if (jj < KR) v += g2r[rt][q] * sg;
      }
      v += __shfl_xor(v, 16);
      v += __shfl_xor(v, 32);
      if (lane < 16)
        fout[(size_t)(pbase + rt) * 512 + FOFF + o] = f2bf_hw(v);
    }
  }
}

// ---------------- K3b: att conv 128->256 per branch, IN-PLACE on fbuf (scale folded) ----
__global__ __launch_bounds__(256, 4) void k_att(
    short* __restrict__ fb,
    const short* __restrict__ wp1f, const float* __restrict__ a1b,
    const short* __restrict__ wp2f, const float* __restrict__ a2b) {
  __shared__ short ptile[64][136];
  int br = blockIdx.y;
  const short* WP = br ? wp2f : wp1f;
  const float* BP = br ? a2b : a1b;
  int FOFF = br ? 256 : 0;

  int tid = threadIdx.x;
  int lane = tid & 63;
  int w = tid >> 6;
  int lr = lane & 15;
  int lg = lane >> 4;
  int p0 = blockIdx.x * 64;

#pragma unroll
  for (int i = 0; i < 4; ++i) {
    int f = i * 256 + tid;
    int row = f >> 4, seg = f & 15;
    *(float4*)&ptile[row][seg * 8] =
        *(const float4*)(fb + (size_t)(p0 + row) * 512 + FOFF + seg * 8);
  }
  __syncthreads();

  bf16x8 af[4][4];
#pragma unroll
  for (int rt = 0; rt < 4; ++rt)
#pragma unroll
    for (int kt = 0; kt < 4; ++kt)
      af[rt][kt] = *(const bf16x8*)&ptile[rt * 16 + lr][kt * 32 + lg * 8];

#pragma unroll
  for (int cc = 0; cc < 4; ++cc) {
    int ct = w * 4 + cc;
    int o = ct * 16 + lr;
    bf16x8 bfr[4];
#pragma unroll
    for (int kt = 0; kt < 4; ++kt) bfr[kt] = ((const bf16x8*)WP)[(kt * 16 + ct) * 64 + lane];
    float bia = BP[o];
#pragma unroll
    for (int rt = 0; rt < 4; ++rt) {
      f32x4 acc = {0.f, 0.f, 0.f, 0.f};
#pragma unroll
      for (int kt = 0; kt < 4; ++kt) acc = MFMA(af[rt][kt], bfr[kt], acc);
#pragma unroll
      for (int q = 0; q < 4; ++q) {
        float v = fmaxf(acc[q] + bia, 0.f);
        fb[(size_t)(p0 + rt * 16 + lg * 4 + q) * 512 + FOFF + o] = f2bf_hw(v);
      }
    }
  }
}

// ---------------- K4: out = relu(f @ (wf*sf)^T + bf), B staged via global_load_lds ------
// b_s is LINEAR [256][64] (gload_lds needs contiguous lane*16B dests). 16B-chunk XOR
// swizzle chunk^=(row&7) applied BOTH on the per-lane global source during staging and
// on the ds_read address (rule #21: both-sides involution) -> conflict-free b128 reads.
__global__ __launch_bounds__(256, 4) void k_final(
    const short* __restrict__ fbuf, const short* __restrict__ wff,
    const float* __restrict__ bfv, float* __restrict__ out) {
  __shared__ short b_s[256][64];   // 32 KB linear
  int tid = threadIdx.x;
  int lane = tid & 63;
  int w = tid >> 6;
  int lr = lane & 15;
  int lg = lane >> 4;
  int ob = blockIdx.x;
  int p0 = blockIdx.y * 256;
  int rtg = ob * 4 + w;

  int srow_off = lane >> 3;        // 0..7 within an 8-row issue
  int schunk = lane & 7;           // physical 16B chunk this lane fills

  f32x4 acc[16];
#pragma unroll
  for (int ct = 0; ct < 16; ++ct) acc[ct] = (f32x4){0.f, 0.f, 0.f, 0.f};

  for (int kc = 0; kc < 512; kc += 64) {
    __syncthreads();
    // stage 256 rows x 64ch via DMA: 4 waves x 8 issues x 1KB
#pragma unroll
    for (int i = 0; i < 8; ++i) {
      int rows_base = w * 64 + i * 8;
      int row = rows_base + srow_off;
      int csw = schunk ^ (row & 7);   // inverse-swizzled SOURCE
      const short* src = fbuf + (size_t)(p0 + row) * 512 + kc + csw * 8;
      gload16(src, &b_s[rows_base][0]);
    }
    __syncthreads();
    int kt = kc >> 5;
    bf16x8 a0 = ((const bf16x8*)wff)[((size_t)(kt + 0) * 32 + rtg) * 64 + lane];
    bf16x8 a1 = ((const bf16x8*)wff)[((size_t)(kt + 1) * 32 + rtg) * 64 + lane];
    int sw0 = (lg ^ (lr & 7)) * 8;          // swizzled read: logical chunk lg
    int sw1 = ((4 | lg) ^ (lr & 7)) * 8;    // logical chunk 4+lg
#pragma unroll
    for (int ct = 0; ct < 16; ++ct) {
      bf16x8 bb0 = *(const bf16x8*)&b_s[ct * 16 + lr][sw0];
      bf16x8 bb1 = *(const bf16x8*)&b_s[ct * 16 + lr][sw1];
      acc[ct] = MFMA(a0, bb0, acc[ct]);
      acc[ct] = MFMA(a1, bb1, acc[ct]);
    }
  }

  int b = p0 >> 11;
  int nb = p0 & (NN - 1);
#pragma unroll
  for (int q = 0; q < 4; ++q) {
    int o = rtg * 16 + lg * 4 + q;
    float bia = bfv[o];
#pragma unroll
    for (int ct = 0; ct < 16; ++ct) {
      int n = nb + ct * 16 + lr;
      float v = fmaxf(acc[ct][q] + bia, 0.f);
      out[((size_t)b * 512 + o) * NN + n] = v;
    }
  }
}

extern "C" void kernel_launch(void* const* d_in, const int* in_sizes, int n_in,
                              void* d_out, int out_size, void* d_ws, size_t ws_size,
                              hipStream_t stream) {
  const float* x      = (const float*)d_in[0];
  const float* lw     = (const float*)d_in[1];
  const float* ls     = (const float*)d_in[2];
  const float* lb     = (const float*)d_in[3];
  const float* w1     = (const float*)d_in[4];
  const float* s1     = (const float*)d_in[5];
  const float* b1     = (const float*)d_in[6];
  const float* w2     = (const float*)d_in[7];
  const float* s2     = (const float*)d_in[8];
  const float* b2     = (const float*)d_in[9];
  const float* w3     = (const float*)d_in[10];
  const float* s3     = (const float*)d_in[11];
  const float* b3     = (const float*)d_in[12];
  const float* w4     = (const float*)d_in[13];
  const float* s4     = (const float*)d_in[14];
  const float* b4     = (const float*)d_in[15];
  const float* a1_att = (const float*)d_in[16];
  const float* a1_w   = (const float*)d_in[17];
  const float* a1_s   = (const float*)d_in[18];
  const float* a1_b   = (const float*)d_in[19];
  const float* a2_att = (const float*)d_in[20];
  const float* a2_w   = (const float*)d_in[21];
  const float* a2_s   = (const float*)d_in[22];
  const float* a2_b   = (const float*)d_in[23];
  const float* wf     = (const float*)d_in[24];
  const float* sf     = (const float*)d_in[25];
  const float* bf     = (const float*)d_in[26];
  float* out = (float*)d_out;

  char* ws = (char*)d_ws;
  float* h   = (float*)ws;                          ws += (size_t)BB * NN * 8 * 4;
  float* xx  = (float*)ws;                          ws += (size_t)BB * NN * 4;
  int* knn_idx = (int*)ws;                          ws += (size_t)BB * NN * 16 * 4;
  short* fbuf  = (short*)ws;                        ws += (size_t)BB * NN * 512 * 2;
  short* w1f   = (short*)ws;                        ws += 1 * 4 * 64 * 8 * 2;
  short* w3f   = (short*)ws;                        ws += 1 * 4 * 64 * 8 * 2;
  short* w2f   = (short*)ws;                        ws += 2 * 8 * 64 * 8 * 2;
  short* w4f   = (short*)ws;                        ws += 2 * 8 * 64 * 8 * 2;
  short* wa1f  = (short*)ws;                        ws += 4 * 8 * 64 * 8 * 2;
  short* wa2f  = (short*)ws;                        ws += 4 * 8 * 64 * 8 * 2;
  short* wp1f  = (short*)ws;                        ws += 4 * 16 * 64 * 8 * 2;
  short* wp2f  = (short*)ws;                        ws += 4 * 16 * 64 * 8 * 2;
  short* wff   = (short*)ws;                        ws += 16 * 32 * 64 * 8 * 2;

  k_prep<<<dim3(744 + 512), dim3(64), 0, stream>>>(
      w1, s1, w3, s3, w2, s2, w4, s4, a1_att, a2_att,
      a1_w, a1_s, a2_w, a2_s, wf, sf,
      w1f, w3f, w2f, w4f, wa1f, wa2f, wp1f, wp2f, wff,
      x, lw, ls, lb, h, xx);

  k_knn<<<dim3(512), dim3(512), 0, stream>>>(h, xx, knn_idx);
  k_branch_all<<<dim3(BB * NN / 8, 2), dim3(512), 0, stream>>>(
      h, knn_idx,
      w1f, b1, w2f, b2, wa1f,
      w3f, b3, w4f, b4, wa2f, fbuf);
  k_att<<<dim3(BB * NN / 64, 2), dim3(256), 0, stream>>>(
      fbuf, wp1f, a1_b, wp2f, a2_b);
  k_final<<<dim3(8, 128), dim3(256), 0, stream>>>(fbuf, wff, bf, out);
}

// Round 17
// 242.886 us; speedup vs baseline: 1.2983x; 1.0003x over previous
//
#include <hip/hip_runtime.h>
#include <hip/hip_bf16.h>
#include <math.h>

#define BB 16
#define NN 2048

typedef short bf16x8 __attribute__((ext_vector_type(8)));
typedef float f32x4 __attribute__((ext_vector_type(4)));
typedef unsigned long long u64;

#define MFMA(a, b, c) __builtin_amdgcn_mfma_f32_16x16x32_bf16(a, b, c, 0, 0, 0)

static __device__ __forceinline__ short f2bf(float f) {
  union { float f; unsigned u; } v; v.f = f;
  unsigned r = v.u + 0x7fffu + ((v.u >> 16) & 1u);
  return (short)(r >> 16);
}
static __device__ __forceinline__ short f2bf_hw(float f) {
  unsigned u;
  asm("v_cvt_pk_bf16_f32 %0, %1, %1" : "=v"(u) : "v"(f));
  return (short)u;
}
static __device__ __forceinline__ unsigned f2bf2(float lo, float hi) {
  unsigned u;
  asm("v_cvt_pk_bf16_f32 %0, %1, %2" : "=v"(u) : "v"(lo), "v"(hi));
  return u;
}
static __device__ __forceinline__ void gload16(const void* g, void* l) {
  __builtin_amdgcn_global_load_lds(
      (const __attribute__((address_space(1))) void*)g,
      (__attribute__((address_space(3))) void*)l, 16, 0, 0);
}

// ---------------- K0: fused weight-pack (BN scale folded) + h/xx compute ----------------
__global__ __launch_bounds__(64) void k_prep(
    const float* __restrict__ w1, const float* __restrict__ s1,
    const float* __restrict__ w3, const float* __restrict__ s3,
    const float* __restrict__ w2, const float* __restrict__ s2,
    const float* __restrict__ w4, const float* __restrict__ s4,
    const float* __restrict__ a1_att, const float* __restrict__ a2_att,
    const float* __restrict__ a1_w, const float* __restrict__ a1s,
    const float* __restrict__ a2_w, const float* __restrict__ a2s,
    const float* __restrict__ wf, const float* __restrict__ sf,
    short* __restrict__ w1f, short* __restrict__ w3f,
    short* __restrict__ w2f, short* __restrict__ w4f,
    short* __restrict__ wa1f, short* __restrict__ wa2f,
    short* __restrict__ wp1f, short* __restrict__ wp2f,
    short* __restrict__ wff,
    const float* __restrict__ x, const float* __restrict__ lw,
    const float* __restrict__ ls, const float* __restrict__ lb,
    float* __restrict__ h, float* __restrict__ xx) {
  int bb = blockIdx.x;
  if (bb >= 744) {
    int p = (bb - 744) * 64 + threadIdx.x;
    int b = p >> 11;
    int n = p & (NN - 1);
    const float* xb = x + (size_t)b * 3 * NN + n;
    float x0 = xb[0], x1 = xb[NN], x2 = xb[2 * NN];
    float hv[8];
    float ss = 0.f;
#pragma unroll
    for (int o = 0; o < 8; ++o) {
      float v = x0 * lw[o * 3 + 0] + x1 * lw[o * 3 + 1] + x2 * lw[o * 3 + 2];
      v = fmaxf(v * ls[o] + lb[o], 0.f);
      hv[o] = v;
      ss += v * v;  // same order as k_knn inner product -> self-dist exactly 0
    }
    float4* hp = (float4*)(h + (size_t)p * 8);
    hp[0] = make_float4(hv[0], hv[1], hv[2], hv[3]);
    hp[1] = make_float4(hv[4], hv[5], hv[6], hv[7]);
    xx[p] = ss;
    return;
  }
  const float* src;
  const float* scl;
  short* dst;
  int O, C, base;
  if (bb < 4)        { src = w1;     scl = s1;  dst = w1f;  O = 64;  C = 16;  base = 0; }
  else if (bb < 8)   { src = w3;     scl = s3;  dst = w3f;  O = 64;  C = 16;  base = 4; }
  else if (bb < 24)  { src = w2;     scl = s2;  dst = w2f;  O = 128; C = 64;  base = 8; }
  else if (bb < 40)  { src = w4;     scl = s4;  dst = w4f;  O = 128; C = 64;  base = 24; }
  else if (bb < 72)  { src = a1_att; scl = 0;   dst = wa1f; O = 128; C = 128; base = 40; }
  else if (bb < 104) { src = a2_att; scl = 0;   dst = wa2f; O = 128; C = 128; base = 72; }
  else if (bb < 168) { src = a1_w;   scl = a1s; dst = wp1f; O = 256; C = 128; base = 104; }
  else if (bb < 232) { src = a2_w;   scl = a2s; dst = wp2f; O = 256; C = 128; base = 168; }
  else               { src = wf;     scl = sf;  dst = wff;  O = 512; C = 512; base = 232; }
  int blk = bb - base;
  int NCT = O >> 4;
  int ct = blk % NCT;
  int kt = blk / NCT;
  int l = threadIdx.x;
  int col = ct * 16 + (l & 15);
  float sc = scl ? scl[col] : 1.f;
  bf16x8 v;
#pragma unroll
  for (int i = 0; i < 8; ++i) {
    int k = kt * 32 + ((l >> 4) << 3) + i;
    v[i] = (k < C) ? f2bf(src[(size_t)col * C + k] * sc) : (short)0;
  }
  ((bf16x8*)dst)[(size_t)blk * 64 + l] = v;
}

// ---------------- K2: kNN top-16 (r12 proven version: LDS staging, shared thresholds) ----
__global__ __launch_bounds__(512, 4) void k_knn(const float* __restrict__ h,
                                                const float* __restrict__ xx,
                                                int* __restrict__ knn_idx) {
  __shared__ __align__(16) unsigned char smem[52224];
  float4* sh4 = (float4*)smem;
  float* sxx = (float*)(smem + 16384);
  unsigned* thr = (unsigned*)(smem + 18432);
  u64* stkb = (u64*)(smem + 18688);

  int tid = threadIdx.x;
  int lane = tid & 63;
  int w = tid >> 6;
  int blk = blockIdx.x;
  int b = blk >> 5;
  int qloc = ((blk & 31) << 6) + lane;
  int p = (b << 11) + qloc;
  const float* hb = h + ((size_t)b << 11) * 8;
  const float* xxb = xx + ((size_t)b << 11);

  const float4* qp = (const float4*)(hb + (size_t)qloc * 8);
  float4 q0 = qp[0], q1 = qp[1];
  float xq = xxb[qloc];

  if (tid < 64) thr[tid] = 0x007FFFFFu;
  __syncthreads();

  u64* stkrow = stkb + tid * 8;
  u64 a[16];
#pragma unroll
  for (int i = 0; i < 16; ++i) a[i] = 0ULL;
  int cnt = 0;

  auto inner8 = [&](int s) -> float {
    float4 a0 = sh4[(w * 64 + s) * 2 + 0];
    float4 a1 = sh4[(w * 64 + s) * 2 + 1];
    return q0.x * a0.x + q0.y * a0.y + q0.z * a0.z + q0.w * a0.w +
           q1.x * a1.x + q1.y * a1.y + q1.z * a1.z + q1.w * a1.w;
  };
  auto mkkey = [&](float d, int mg) -> u64 {
    unsigned uu = __float_as_uint(d);
    unsigned key = ((int)uu >= 0) ? (uu | 0x80000000u) : ~uu;
    return ((u64)key << 32) | (unsigned)(NN - 1 - mg);
  };

  auto flush = [&]() {
    u64 c[8];
#pragma unroll
    for (int j = 0; j < 8; ++j) {
      u64 v = stkrow[j];
      c[j] = (j < cnt) ? v : 0ULL;
    }
    cnt = 0;
#pragma unroll
    for (int k = 2; k <= 8; k <<= 1)
#pragma unroll
      for (int j = k >> 1; j > 0; j >>= 1)
#pragma unroll
        for (int i = 0; i < 8; ++i) {
          int l = i ^ j;
          if (l > i) {
            bool up = ((i & k) == 0);
            u64 xi = c[i], xl = c[l];
            bool sw = up ? (xi > xl) : (xi < xl);
            if (sw) { c[i] = xl; c[l] = xi; }
          }
        }
    u64 m[16];
#pragma unroll
    for (int i = 0; i < 16; ++i) {
      u64 bi = (i < 8) ? c[7 - i] : 0ULL;
      m[i] = (a[i] > bi) ? a[i] : bi;
    }
#pragma unroll
    for (int j = 8; j > 0; j >>= 1)
#pragma unroll
      for (int i = 0; i < 16; ++i) {
        int l = i ^ j;
        if (l > i && m[i] > m[l]) { u64 t = m[i]; m[i] = m[l]; m[l] = t; }
      }
#pragma unroll
    for (int i = 0; i < 16; ++i) a[i] = m[i];
  };

  int sbase = w * 256;
  float4 r0, r1;
  float rx;
  {
    const float* cp = hb + (size_t)(sbase + lane) * 8;
    r0 = *(const float4*)cp;
    r1 = *(const float4*)(cp + 4);
    rx = xxb[sbase + lane];
  }
  for (int c2 = 0; c2 < 4; ++c2) {
    sh4[(w * 64 + lane) * 2 + 0] = r0;
    sh4[(w * 64 + lane) * 2 + 1] = r1;
    sxx[w * 64 + lane] = rx;
    if (c2 < 3) {
      const float* cp = hb + (size_t)(sbase + (c2 + 1) * 64 + lane) * 8;
      r0 = *(const float4*)cp;
      r1 = *(const float4*)(cp + 4);
      rx = xxb[sbase + (c2 + 1) * 64 + lane];
    }
    int mg0 = sbase + c2 * 64;
    int sstart = 0;
    if (c2 == 0) {
      u64 cc[16];
#pragma unroll
      for (int j = 0; j < 16; ++j) cc[j] = mkkey(2.f * inner8(j) - xq - sxx[w * 64 + j], mg0 + j);
#pragma unroll
      for (int k = 2; k <= 16; k <<= 1)
#pragma unroll
        for (int j = k >> 1; j > 0; j >>= 1)
#pragma unroll
          for (int i = 0; i < 16; ++i) {
            int l = i ^ j;
            if (l > i) {
              bool up = ((i & k) == 0);
              u64 xi = cc[i], xl = cc[l];
              bool sw = up ? (xi > xl) : (xi < xl);
              if (sw) { cc[i] = xl; cc[l] = xi; }
            }
          }
#pragma unroll
      for (int i = 0; i < 16; ++i) a[i] = cc[i];
      atomicMax(&thr[lane], (unsigned)(a[0] >> 32));
      sstart = 16;
    }
    for (int s16 = sstart; s16 < 64; s16 += 16) {
      unsigned t32 = thr[lane];
      unsigned tu = (t32 & 0x80000000u) ? (t32 & 0x7fffffffu) : ~t32;
      float thrF = __uint_as_float(tu);
#pragma unroll
      for (int s4 = 0; s4 < 16; s4 += 4) {
        int s = s16 + s4;
        float4 xm4 = *(const float4*)&sxx[w * 64 + s];
#pragma unroll
        for (int u = 0; u < 4; ++u) {
          float xm = (u == 0) ? xm4.x : (u == 1) ? xm4.y : (u == 2) ? xm4.z : xm4.w;
          float d = 2.f * inner8(s + u) - xq - xm;
          if (d >= thrF) { stkrow[cnt] = mkkey(d, mg0 + s + u); cnt++; }
        }
        if (__any(cnt >= 5)) {
          flush();
          atomicMax(&thr[lane], (unsigned)(a[0] >> 32));
          unsigned t2 = thr[lane];
          unsigned tu2 = (t2 & 0x80000000u) ? (t2 & 0x7fffffffu) : ~t2;
          thrF = __uint_as_float(tu2);
        }
      }
    }
  }
  if (__any(cnt > 0)) flush();

  u64* M1 = (u64*)smem;
  u64* M2 = (u64*)(smem + 34816);
  u64* M3 = (u64*)smem;

  auto mergeLds = [&](const u64* src) {
    u64 m[16];
#pragma unroll
    for (int i = 0; i < 16; ++i) {
      u64 bi = src[15 - i];
      m[i] = (a[i] > bi) ? a[i] : bi;
    }
#pragma unroll
    for (int j = 8; j > 0; j >>= 1)
#pragma unroll
      for (int i = 0; i < 16; ++i) {
        int l = i ^ j;
        if (l > i && m[i] > m[l]) { u64 t = m[i]; m[i] = m[l]; m[l] = t; }
      }
#pragma unroll
    for (int i = 0; i < 16; ++i) a[i] = m[i];
  };

  __syncthreads();
  if (w >= 4) {
#pragma unroll
    for (int i = 0; i < 16; ++i) M1[((w - 4) * 64 + lane) * 17 + i] = a[i];
  }
  __syncthreads();
  if (w < 4) mergeLds(&M1[(w * 64 + lane) * 17]);
  __syncthreads();
  if (w == 2 || w == 3) {
#pragma unroll
    for (int i = 0; i < 16; ++i) M2[((w - 2) * 64 + lane) * 17 + i] = a[i];
  }
  __syncthreads();
  if (w < 2) mergeLds(&M2[(w * 64 + lane) * 17]);
  __syncthreads();
  if (w == 1) {
#pragma unroll
    for (int i = 0; i < 16; ++i) M3[lane * 17 + i] = a[i];
  }
  __syncthreads();
  if (w == 0) {
    mergeLds(&M3[lane * 17]);
    int ids[16];
#pragma unroll
    for (int r = 0; r < 16; ++r)
      ids[r] = (NN - 1) - (int)(unsigned)(a[15 - r] & 0xFFFFFFFFULL);
    int4* op = (int4*)(knn_idx + (size_t)p * 16);
    op[0] = make_int4(ids[0], ids[1], ids[2], ids[3]);
    op[1] = make_int4(ids[4], ids[5], ids[6], ids[7]);
    op[2] = make_int4(ids[8], ids[9], ids[10], ids[11]);
    op[3] = make_int4(ids[12], ids[13], ids[14], ids[15]);
  }
}

// ---------------- K3: edge->conv1->conv2->score->pool, g2 halved -> 4 blocks/CU ----------
// LDS: g1[128][72]=18.4KB + g2[64][136]=17.4KB (e_s[128][40] overlays g2's region).
// Phases C/D run per row-half with 2 extra barriers; arithmetic identical to r16.
__global__ __launch_bounds__(512, 8) void k_branch_all(
    const float* __restrict__ h, const int* __restrict__ knn_idx,
    const short* __restrict__ w1f, const float* __restrict__ b1,
    const short* __restrict__ w2f, const float* __restrict__ b2,
    const short* __restrict__ wa1f,
    const short* __restrict__ w3f, const float* __restrict__ b3,
    const short* __restrict__ w4f, const float* __restrict__ b4,
    const short* __restrict__ wa2f,
    short* __restrict__ fout) {
  __shared__ __align__(16) unsigned char smem[35840];
  short (*g1_s)[72]  = (short(*)[72])smem;               // [128][72], phases B-C
  short (*g2_s)[136] = (short(*)[136])(smem + 18432);    // [64][136], per half (C-D)
  short (*e_s)[40]   = (short(*)[40])(smem + 18432);     // [128][40], phases A-B (overlay)

  int br = blockIdx.y;
  const short* W1 = br ? w3f : w1f;
  const float* B1 = br ? b3 : b1;
  const short* W2 = br ? w4f : w2f;
  const float* B2 = br ? b4 : b2;
  const short* WA = br ? wa2f : wa1f;
  int KR = br ? 12 : 16;
  int FOFF = br ? 256 : 0;

  int tid = threadIdx.x;
  int lane = tid & 63;
  int w = tid >> 6;
  int lr = lane & 15;
  int lg = lane >> 4;
  int pbase = blockIdx.x * 8;
  const float* hb = h + ((size_t)(pbase & ~(NN - 1))) * 8;

  // Phase A: edge features, all 512 threads (quarter-row each)
  {
    int t = tid >> 2, q4 = tid & 3;
    int pt = t >> 4, j = t & 15;
    int p = pbase + pt;
    bool real = (j < KR);
    unsigned dd = 0, cc2 = 0;
    if (real) {
      int id = knn_idx[(size_t)p * 16 + j];
      const float* cp = h + (size_t)p * 8 + q4 * 2;
      const float* np_ = hb + (size_t)id * 8 + q4 * 2;
      float2 cv = *(const float2*)cp;
      float2 nv = *(const float2*)np_;
      dd = f2bf2(nv.x - cv.x, nv.y - cv.y);
      cc2 = f2bf2(cv.x, cv.y);
    }
    *(unsigned*)&e_s[t][q4 * 2] = dd;
    *(unsigned*)&e_s[t][8 + q4 * 2] = cc2;
    *(uint2*)&e_s[t][16 + q4 * 4] = make_uint2(0, 0);  // K-pad
  }
  __syncthreads();

  // Phase B: conv1 16->64 (scale folded into W1), all 128 rows
  {
    int ct = w & 3;
    int rhalf = w >> 2;
    int o = ct * 16 + lr;
    bf16x8 bfrag = ((const bf16x8*)W1)[ct * 64 + lane];
    float bia = B1[o];
#pragma unroll
    for (int rt = 0; rt < 4; ++rt) {
      int rr = rhalf * 4 + rt;
      bf16x8 af = *(const bf16x8*)&e_s[rr * 16 + lr][lg * 8];
      f32x4 acc = {0.f, 0.f, 0.f, 0.f};
      acc = MFMA(af, bfrag, acc);
#pragma unroll
      for (int q = 0; q < 4; ++q) {
        g1_s[rr * 16 + lg * 4 + q][o] = f2bf_hw(fmaxf(acc[q] + bia, 0.f));
      }
    }
  }
  __syncthreads();  // e_s dead; its bytes become g2_s

  // Phases C+D per row-half (4 points each)
  float g2r[4][4];
#pragma unroll 1
  for (int h2 = 0; h2 < 2; ++h2) {
    // Phase C: conv2 64->128 on rows [h2*64, h2*64+64)
    {
      int ct = w;
      int o = ct * 16 + lr;
      bf16x8 bf0 = ((const bf16x8*)W2)[(0 * 8 + ct) * 64 + lane];
      bf16x8 bf1 = ((const bf16x8*)W2)[(1 * 8 + ct) * 64 + lane];
      float bia = B2[o];
#pragma unroll
      for (int rt = 0; rt < 4; ++rt) {
        int rg = h2 * 64 + rt * 16;
        bf16x8 a0 = *(const bf16x8*)&g1_s[rg + lr][lg * 8];
        bf16x8 a1 = *(const bf16x8*)&g1_s[rg + lr][32 + lg * 8];
        f32x4 acc = {0.f, 0.f, 0.f, 0.f};
        acc = MFMA(a0, bf0, acc);
        acc = MFMA(a1, bf1, acc);
#pragma unroll
        for (int q = 0; q < 4; ++q) {
          float v = fmaxf(acc[q] + bia, 0.f);
          g2r[rt][q] = v;
          g2_s[rt * 16 + lg * 4 + q][o] = f2bf_hw(v);
        }
      }
    }
    __syncthreads();

    // Phase D: att score (sigmoid)*g2, masked k-sum -> fbuf
    {
      int ct = w;
      int o = ct * 16 + lr;
      bf16x8 bfr[4];
#pragma unroll
      for (int kt = 0; kt < 4; ++kt) bfr[kt] = ((const bf16x8*)WA)[(kt * 8 + ct) * 64 + lane];
#pragma unroll
      for (int rt = 0; rt < 4; ++rt) {
        f32x4 acc = {0.f, 0.f, 0.f, 0.f};
#pragma unroll
        for (int kt = 0; kt < 4; ++kt) {
          bf16x8 a = *(const bf16x8*)&g2_s[rt * 16 + lr][kt * 32 + lg * 8];
          acc = MFMA(a, bfr[kt], acc);
        }
        float v = 0.f;
#pragma unroll
        for (int q = 0; q < 4; ++q) {
          int jj = lg * 4 + q;
          float sg = __builtin_amdgcn_rcpf(1.f + __expf(-acc[q]));
          if (jj < KR) v += g2r[rt][q] * sg;
        }
        v += __shfl_xor(v, 16);
        v += __shfl_xor(v, 32);
        if (lane < 16)
          fout[(size_t)(pbase + h2 * 4 + rt) * 512 + FOFF + o] = f2bf_hw(v);
      }
    }
    __syncthreads();  // g2_s free for next half
  }
}

// ---------------- K3b: att conv 128->256 per branch, IN-PLACE on fbuf (scale folded) ----
__global__ __launch_bounds__(256, 4) void k_att(
    short* __restrict__ fb,
    const short* __restrict__ wp1f, const float* __restrict__ a1b,
    const short* __restrict__ wp2f, const float* __restrict__ a2b) {
  __shared__ short ptile[64][136];
  int br = blockIdx.y;
  const short* WP = br ? wp2f : wp1f;
  const float* BP = br ? a2b : a1b;
  int FOFF = br ? 256 : 0;

  int tid = threadIdx.x;
  int lane = tid & 63;
  int w = tid >> 6;
  int lr = lane & 15;
  int lg = lane >> 4;
  int p0 = blockIdx.x * 64;

#pragma unroll
  for (int i = 0; i < 4; ++i) {
    int f = i * 256 + tid;
    int row = f >> 4, seg = f & 15;
    *(float4*)&ptile[row][seg * 8] =
        *(const float4*)(fb + (size_t)(p0 + row) * 512 + FOFF + seg * 8);
  }
  __syncthreads();

  bf16x8 af[4][4];
#pragma unroll
  for (int rt = 0; rt < 4; ++rt)
#pragma unroll
    for (int kt = 0; kt < 4; ++kt)
      af[rt][kt] = *(const bf16x8*)&ptile[rt * 16 + lr][kt * 32 + lg * 8];

#pragma unroll
  for (int cc = 0; cc < 4; ++cc) {
    int ct = w * 4 + cc;
    int o = ct * 16 + lr;
    bf16x8 bfr[4];
#pragma unroll
    for (int kt = 0; kt < 4; ++kt) bfr[kt] = ((const bf16x8*)WP)[(kt * 16 + ct) * 64 + lane];
    float bia = BP[o];
#pragma unroll
    for (int rt = 0; rt < 4; ++rt) {
      f32x4 acc = {0.f, 0.f, 0.f, 0.f};
#pragma unroll
      for (int kt = 0; kt < 4; ++kt) acc = MFMA(af[rt][kt], bfr[kt], acc);
#pragma unroll
      for (int q = 0; q < 4; ++q) {
        float v = fmaxf(acc[q] + bia, 0.f);
        fb[(size_t)(p0 + rt * 16 + lg * 4 + q) * 512 + FOFF + o] = f2bf_hw(v);
      }
    }
  }
}

// ---------------- K4: out = relu(f @ (wf*sf)^T + bf), B staged via global_load_lds ------
__global__ __launch_bounds__(256, 4) void k_final(
    const short* __restrict__ fbuf, const short* __restrict__ wff,
    const float* __restrict__ bfv, float* __restrict__ out) {
  __shared__ short b_s[256][64];   // 32 KB linear
  int tid = threadIdx.x;
  int lane = tid & 63;
  int w = tid >> 6;
  int lr = lane & 15;
  int lg = lane >> 4;
  int ob = blockIdx.x;
  int p0 = blockIdx.y * 256;
  int rtg = ob * 4 + w;

  int srow_off = lane >> 3;
  int schunk = lane & 7;

  f32x4 acc[16];
#pragma unroll
  for (int ct = 0; ct < 16; ++ct) acc[ct] = (f32x4){0.f, 0.f, 0.f, 0.f};

  for (int kc = 0; kc < 512; kc += 64) {
    __syncthreads();
#pragma unroll
    for (int i = 0; i < 8; ++i) {
      int rows_base = w * 64 + i * 8;
      int row = rows_base + srow_off;
      int csw = schunk ^ (row & 7);
      const short* src = fbuf + (size_t)(p0 + row) * 512 + kc + csw * 8;
      gload16(src, &b_s[rows_base][0]);
    }
    __syncthreads();
    int kt = kc >> 5;
    bf16x8 a0 = ((const bf16x8*)wff)[((size_t)(kt + 0) * 32 + rtg) * 64 + lane];
    bf16x8 a1 = ((const bf16x8*)wff)[((size_t)(kt + 1) * 32 + rtg) * 64 + lane];
    int sw0 = (lg ^ (lr & 7)) * 8;
    int sw1 = ((4 | lg) ^ (lr & 7)) * 8;
#pragma unroll
    for (int ct = 0; ct < 16; ++ct) {
      bf16x8 bb0 = *(const bf16x8*)&b_s[ct * 16 + lr][sw0];
      bf16x8 bb1 = *(const bf16x8*)&b_s[ct * 16 + lr][sw1];
      acc[ct] = MFMA(a0, bb0, acc[ct]);
      acc[ct] = MFMA(a1, bb1, acc[ct]);
    }
  }

  int b = p0 >> 11;
  int nb = p0 & (NN - 1);
#pragma unroll
  for (int q = 0; q < 4; ++q) {
    int o = rtg * 16 + lg * 4 + q;
    float bia = bfv[o];
#pragma unroll
    for (int ct = 0; ct < 16; ++ct) {
      int n = nb + ct * 16 + lr;
      float v = fmaxf(acc[ct][q] + bia, 0.f);
      out[((size_t)b * 512 + o) * NN + n] = v;
    }
  }
}

extern "C" void kernel_launch(void* const* d_in, const int* in_sizes, int n_in,
                              void* d_out, int out_size, void* d_ws, size_t ws_size,
                              hipStream_t stream) {
  const float* x      = (const float*)d_in[0];
  const float* lw     = (const float*)d_in[1];
  const float* ls     = (const float*)d_in[2];
  const float* lb     = (const float*)d_in[3];
  const float* w1     = (const float*)d_in[4];
  const float* s1     = (const float*)d_in[5];
  const float* b1     = (const float*)d_in[6];
  const float* w2     = (const float*)d_in[7];
  const float* s2     = (const float*)d_in[8];
  const float* b2     = (const float*)d_in[9];
  const float* w3     = (const float*)d_in[10];
  const float* s3     = (const float*)d_in[11];
  const float* b3     = (const float*)d_in[12];
  const float* w4     = (const float*)d_in[13];
  const float* s4     = (const float*)d_in[14];
  const float* b4     = (const float*)d_in[15];
  const float* a1_att = (const float*)d_in[16];
  const float* a1_w   = (const float*)d_in[17];
  const float* a1_s   = (const float*)d_in[18];
  const float* a1_b   = (const float*)d_in[19];
  const float* a2_att = (const float*)d_in[20];
  const float* a2_w   = (const float*)d_in[21];
  const float* a2_s   = (const float*)d_in[22];
  const float* a2_b   = (const float*)d_in[23];
  const float* wf     = (const float*)d_in[24];
  const float* sf     = (const float*)d_in[25];
  const float* bf     = (const float*)d_in[26];
  float* out = (float*)d_out;

  char* ws = (char*)d_ws;
  float* h   = (float*)ws;                          ws += (size_t)BB * NN * 8 * 4;
  float* xx  = (float*)ws;                          ws += (size_t)BB * NN * 4;
  int* knn_idx = (int*)ws;                          ws += (size_t)BB * NN * 16 * 4;
  short* fbuf  = (short*)ws;                        ws += (size_t)BB * NN * 512 * 2;
  short* w1f   = (short*)ws;                        ws += 1 * 4 * 64 * 8 * 2;
  short* w3f   = (short*)ws;                        ws += 1 * 4 * 64 * 8 * 2;
  short* w2f   = (short*)ws;                        ws += 2 * 8 * 64 * 8 * 2;
  short* w4f   = (short*)ws;                        ws += 2 * 8 * 64 * 8 * 2;
  short* wa1f  = (short*)ws;                        ws += 4 * 8 * 64 * 8 * 2;
  short* wa2f  = (short*)ws;                        ws += 4 * 8 * 64 * 8 * 2;
  short* wp1f  = (short*)ws;                        ws += 4 * 16 * 64 * 8 * 2;
  short* wp2f  = (short*)ws;                        ws += 4 * 16 * 64 * 8 * 2;
  short* wff   = (short*)ws;                        ws += 16 * 32 * 64 * 8 * 2;

  k_prep<<<dim3(744 + 512), dim3(64), 0, stream>>>(
      w1, s1, w3, s3, w2, s2, w4, s4, a1_att, a2_att,
      a1_w, a1_s, a2_w, a2_s, wf, sf,
      w1f, w3f, w2f, w4f, wa1f, wa2f, wp1f, wp2f, wff,
      x, lw, ls, lb, h, xx);

  k_knn<<<dim3(512), dim3(512), 0, stream>>>(h, xx, knn_idx);
  k_branch_all<<<dim3(BB * NN / 8, 2), dim3(512), 0, stream>>>(
      h, knn_idx,
      w1f, b1, w2f, b2, wa1f,
      w3f, b3, w4f, b4, wa2f, fbuf);
  k_att<<<dim3(BB * NN / 64, 2), dim3(256), 0, stream>>>(
      fbuf, wp1f, a1_b, wp2f, a2_b);
  k_final<<<dim3(8, 128), dim3(256), 0, stream>>>(fbuf, wff, bf, out);
}